// Round 6
// baseline (4354.206 us; speedup 1.0000x reference)
//
#include <hip/hip_runtime.h>
#include <math.h>

#define N_NODES 50000
#define N_EDGES 800000
#define M_HID   128
#define P_FEAT  256
#define C_OUT   40
#define PWR_ITERS 50
#define FP_ITERS  30
#define KAPPA 0.9f
#define SBLK 256

// ---------------- init ----------------

__global__ void fill_pow(float* buf0, float* ss, int n, float val) {
    int i = blockIdx.x * blockDim.x + threadIdx.x;
    if (i < n) buf0[i] = val;
    if (blockIdx.x == 0 && threadIdx.x < 64) ss[threadIdx.x] = (threadIdx.x == 0) ? 1.f : 0.f;
}

// ---------------- power iteration: 4-lane-per-node gather matvec + fused norm ----

__global__ __launch_bounds__(256) void matvec_norm(const int* __restrict__ offs,
                                                   const int* __restrict__ cdst,
                                                   const float* __restrict__ cw,
                                                   const float* __restrict__ vin,
                                                   const float* __restrict__ n2in,
                                                   float* __restrict__ vout,
                                                   float* n2out, int n) {
    int t = blockIdx.x * blockDim.x + threadIdx.x;
    int g = t >> 2, q = t & 3;
    float inv = 1.f / (sqrtf(*n2in) + 1e-12f);
    float a = 0.f;
    if (g < n) {
        int lo = offs[g], hi = offs[g + 1];
        for (int e = lo + q; e < hi; e += 4) a += cw[e] * vin[cdst[e]];
    }
    a += __shfl_xor(a, 1, 64);
    a += __shfl_xor(a, 2, 64);
    a *= inv;
    if (g < n && q == 0) vout[g] = a;
    float s = (q == 0 && g < n) ? a * a : 0.f;
    for (int o = 32; o > 0; o >>= 1) s += __shfl_down(s, o, 64);
    __shared__ float ls[4];
    int lane = threadIdx.x & 63, wid = threadIdx.x >> 6;
    if (lane == 0) ls[wid] = s;
    __syncthreads();
    if (threadIdx.x == 0) atomicAdd(n2out, ls[0] + ls[1] + ls[2] + ls[3]);
}

// ---------------- L1-ball row projection of W ----------------

__global__ __launch_bounds__(128) void project_w(const float* __restrict__ W,
                                                 const float* __restrict__ rho2,
                                                 float* Wp, float* WpT) {
    __shared__ float sa[128];
    __shared__ float ssort[128];
    __shared__ float sc[128];
    __shared__ int cnt2[2];
    int r = blockIdx.x, t = threadIdx.x;
    float radius = KAPPA / sqrtf(*rho2);
    float w0 = W[r * 128 + t];
    float a = fabsf(w0);
    sa[t] = a;
    __syncthreads();
    int rank = 0;
    #pragma unroll 8
    for (int j = 0; j < 128; ++j) {
        float aj = sa[j];
        rank += (aj > a) || (aj == a && j < t);
    }
    ssort[rank] = a;
    __syncthreads();
    sc[t] = ssort[t];
    __syncthreads();
    for (int off = 1; off < 128; off <<= 1) {
        float add = (t >= off) ? sc[t - off] : 0.f;
        __syncthreads();
        sc[t] += add;
        __syncthreads();
    }
    bool flag = ssort[t] * (float)(t + 1) > sc[t] - radius;
    unsigned long long b = __ballot(flag);
    if ((t & 63) == 0) cnt2[t >> 6] = __popcll(b);
    __syncthreads();
    int rho = cnt2[0] + cnt2[1];
    float total = sc[127];
    bool needs = total > radius;
    float theta = (sc[rho - 1] - radius) / (float)rho;
    float o;
    if (needs) {
        float am = a - theta;
        o = (am > 0.f) ? ((w0 > 0.f) ? am : -am) : 0.f;
    } else o = w0;
    Wp[r * 128 + t] = o;
    WpT[t * 128 + r] = o;
}

// ---------------- CSR builds (by src AND by dst) ----------------

__global__ void count_deg_both(const int* __restrict__ src, const int* __restrict__ dst,
                               int* deg_s, int* deg_d, int E) {
    int e = blockIdx.x * blockDim.x + threadIdx.x;
    if (e < E) {
        atomicAdd(&deg_s[src[e]], 1);
        atomicAdd(&deg_d[dst[e]], 1);
    }
}

// 3-kernel multi-block exclusive scan over n+1 entries (deg has n entries).

__global__ __launch_bounds__(SBLK) void scan_local(const int* __restrict__ deg,
                                                   int* __restrict__ offsets,
                                                   int* __restrict__ bsum, int n1) {
    __shared__ int s[SBLK];
    int i = blockIdx.x * SBLK + threadIdx.x;
    int v = (i < n1 - 1) ? deg[i] : 0;
    s[threadIdx.x] = v;
    __syncthreads();
    for (int o = 1; o < SBLK; o <<= 1) {
        int add = (threadIdx.x >= o) ? s[threadIdx.x - o] : 0;
        __syncthreads();
        s[threadIdx.x] += add;
        __syncthreads();
    }
    if (i < n1) offsets[i] = s[threadIdx.x] - v;   // exclusive
    if (threadIdx.x == SBLK - 1) bsum[blockIdx.x] = s[SBLK - 1];
}

__global__ __launch_bounds__(SBLK) void scan_bsum(const int* __restrict__ bsum,
                                                  int* __restrict__ bbase, int nb) {
    __shared__ int s[SBLK];
    int v = (threadIdx.x < nb) ? bsum[threadIdx.x] : 0;
    s[threadIdx.x] = v;
    __syncthreads();
    for (int o = 1; o < SBLK; o <<= 1) {
        int add = (threadIdx.x >= o) ? s[threadIdx.x - o] : 0;
        __syncthreads();
        s[threadIdx.x] += add;
        __syncthreads();
    }
    if (threadIdx.x < nb) bbase[threadIdx.x] = s[threadIdx.x] - v;
}

__global__ __launch_bounds__(SBLK) void scan_add(int* __restrict__ offsets,
                                                 int* __restrict__ cursor,
                                                 const int* __restrict__ bbase, int n1) {
    int i = blockIdx.x * SBLK + threadIdx.x;
    if (i < n1) {
        int o = offsets[i] + bbase[blockIdx.x];
        offsets[i] = o;
        if (i < n1 - 1) cursor[i] = o;
    }
}

__global__ void fill_csr_both(const int* __restrict__ src, const int* __restrict__ dst,
                              const float* __restrict__ w,
                              int* cur_s, int* csr_dst, float* csr_ws,
                              int* cur_d, int* csr_src, float* csr_wd, int E) {
    int e = blockIdx.x * blockDim.x + threadIdx.x;
    if (e < E) {
        int s = src[e], d = dst[e];
        float ww = w[e];
        int ps = atomicAdd(&cur_s[s], 1);
        csr_dst[ps] = d;
        csr_ws[ps] = ww;
        int pd = atomicAdd(&cur_d[d], 1);
        csr_src[pd] = s;
        csr_wd[pd] = ww;
    }
}

// ---------------- small transposes ----------------

__global__ void transpose_om(const float* __restrict__ Om, float* OmT) {
    int idx = blockIdx.x * blockDim.x + threadIdx.x;
    if (idx < 128 * 256) {
        int t = idx / 256, k = idx % 256;
        OmT[k * 128 + t] = Om[idx];
    }
}

__global__ void transpose_x0(const float* __restrict__ X0, float* Xt, int n) {
    __shared__ float tile[32][33];
    int jb = blockIdx.x * 32, tb = blockIdx.y * 32;
    int tx = threadIdx.x, ty = threadIdx.y;
    for (int r = 0; r < 32; r += 8) {
        int t = tb + ty + r, j = jb + tx;
        tile[ty + r][tx] = (j < n) ? X0[(size_t)t * n + j] : 0.f;
    }
    __syncthreads();
    for (int r = 0; r < 32; r += 8) {
        int j = jb + ty + r, t = tb + tx;
        if (j < n) Xt[(size_t)j * 128 + t] = tile[tx][ty + r];
    }
}

// ---------------- one-shot dense GEMM: Ut = F^T @ OmT (64-row tiles) ----------------

__global__ __launch_bounds__(256) void gemm_u(const float* __restrict__ F,
                                              const float* __restrict__ OmT,
                                              float* __restrict__ C, int n) {
    __shared__ float Fs[16][65];
    __shared__ float Bs[16][129];
    int j0 = blockIdx.x * 64;
    int tid = threadIdx.x;
    int tj = tid >> 4, tg = tid & 15;
    float acc[4][8] = {};
    for (int k0 = 0; k0 < 256; k0 += 16) {
        #pragma unroll
        for (int r = 0; r < 4; ++r) {
            int idx = r * 256 + tid;
            int kk = idx >> 6, jj = idx & 63;
            int j = j0 + jj;
            Fs[kk][jj] = (j < n) ? F[(size_t)(k0 + kk) * n + j] : 0.f;
        }
        #pragma unroll
        for (int r = 0; r < 8; ++r) {
            int idx = r * 256 + tid;
            int kk = idx >> 7, tt = idx & 127;
            Bs[kk][tt] = OmT[(k0 + kk) * 128 + tt];
        }
        __syncthreads();
        #pragma unroll
        for (int kk = 0; kk < 16; ++kk) {
            float a[4], b[8];
            #pragma unroll
            for (int u = 0; u < 4; ++u) a[u] = Fs[kk][tj + 16 * u];
            #pragma unroll
            for (int u = 0; u < 8; ++u) b[u] = Bs[kk][tg + 16 * u];
            #pragma unroll
            for (int x = 0; x < 4; ++x)
                #pragma unroll
                for (int y = 0; y < 8; ++y)
                    acc[x][y] += a[x] * b[y];
        }
        __syncthreads();
    }
    #pragma unroll
    for (int x = 0; x < 4; ++x) {
        int j = j0 + tj + 16 * x;
        if (j < n)
            #pragma unroll
            for (int y = 0; y < 8; ++y)
                C[(size_t)j * 128 + tg + 16 * y] = acc[x][y];
    }
}

// ---------------- spmm: wave-per-node gather, 8-wide index preload ----------------

__global__ __launch_bounds__(256) void spmm_csr(const int* __restrict__ offsets,
                                                const int* __restrict__ csr_src,
                                                const float* __restrict__ csr_w,
                                                const float* __restrict__ Xin,
                                                float* __restrict__ Yout, int n) {
    int j = blockIdx.x * 4 + (threadIdx.x >> 6);
    if (j >= n) return;
    int lane = threadIdx.x & 63;
    int lo = offsets[j], hi = offsets[j + 1];
    const float2* __restrict__ X2 = (const float2*)Xin;
    float2 acc = {0.f, 0.f};
    int e = lo;
    for (; e + 8 <= hi; e += 8) {
        int s[8]; float w[8];
        #pragma unroll
        for (int u = 0; u < 8; ++u) { s[u] = csr_src[e + u]; w[u] = csr_w[e + u]; }
        float2 x[8];
        #pragma unroll
        for (int u = 0; u < 8; ++u) x[u] = X2[(size_t)s[u] * 64 + lane];
        #pragma unroll
        for (int u = 0; u < 8; ++u) {
            acc.x += w[u] * x[u].x;
            acc.y += w[u] * x[u].y;
        }
    }
    for (; e < hi; ++e) {
        int s = csr_src[e];
        float w = csr_w[e];
        float2 x = X2[(size_t)s * 64 + lane];
        acc.x += w * x.x;
        acc.y += w * x.y;
    }
    ((float2*)Yout)[(size_t)j * 64 + lane] = acc;
}

// ---------------- gemm_relu: Xt = relu(Yt @ WpT + bt) (64-row tiles) ----------------

__global__ __launch_bounds__(256) void gemm_relu(const float* __restrict__ Yt,
                                                 const float* __restrict__ WpT,
                                                 const float* __restrict__ bt,
                                                 float* __restrict__ Xt, int n) {
    __shared__ float As[16][65];
    __shared__ float Bs[16][129];
    int j0 = blockIdx.x * 64;
    int tid = threadIdx.x;
    int tj = tid >> 4, tg = tid & 15;
    float acc[4][8] = {};
    for (int k0 = 0; k0 < 128; k0 += 16) {
        #pragma unroll
        for (int r = 0; r < 4; ++r) {
            int idx = r * 256 + tid;
            int jj = idx >> 4, kk = idx & 15;
            int j = j0 + jj;
            As[kk][jj] = (j < n) ? Yt[(size_t)j * 128 + k0 + kk] : 0.f;
        }
        #pragma unroll
        for (int r = 0; r < 8; ++r) {
            int idx = r * 256 + tid;
            int kk = idx >> 7, tt = idx & 127;
            Bs[kk][tt] = WpT[(k0 + kk) * 128 + tt];
        }
        __syncthreads();
        #pragma unroll
        for (int kk = 0; kk < 16; ++kk) {
            float a[4], b[8];
            #pragma unroll
            for (int u = 0; u < 4; ++u) a[u] = As[kk][tj + 16 * u];
            #pragma unroll
            for (int u = 0; u < 8; ++u) b[u] = Bs[kk][tg + 16 * u];
            #pragma unroll
            for (int x = 0; x < 4; ++x)
                #pragma unroll
                for (int y = 0; y < 8; ++y)
                    acc[x][y] += a[x] * b[y];
        }
        __syncthreads();
    }
    #pragma unroll
    for (int x = 0; x < 4; ++x) {
        int j = j0 + tj + 16 * x;
        if (j < n)
            #pragma unroll
            for (int y = 0; y < 8; ++y) {
                int c = tg + 16 * y;
                float v = acc[x][y] + bt[(size_t)j * 128 + c];
                Xt[(size_t)j * 128 + c] = (v > 0.f) ? v : 0.f;
            }
    }
}

// ---------------- final: normalize rows + H @ Vw^T ----------------

__global__ __launch_bounds__(256) void final_out(const float* __restrict__ Xt,
                                                 const float* __restrict__ Vw,
                                                 float* __restrict__ out, int n) {
    __shared__ float Vs[40][132];
    int tid = threadIdx.x;
    int jb = blockIdx.x * 64;
    for (int i = tid; i < 40 * 128; i += 256) {
        int c = i >> 7, k = i & 127;
        Vs[c][(k >> 5) * 33 + (k & 31)] = Vw[i];
    }
    int g = tid >> 2, q = tid & 3;
    int j = jb + g;
    float4 xv[8];
    float ss = 0.f;
    if (j < n) {
        const float4* X4 = (const float4*)(Xt + (size_t)j * 128 + q * 32);
        #pragma unroll
        for (int u = 0; u < 8; ++u) {
            xv[u] = X4[u];
            ss += xv[u].x * xv[u].x + xv[u].y * xv[u].y
                + xv[u].z * xv[u].z + xv[u].w * xv[u].w;
        }
    } else {
        #pragma unroll
        for (int u = 0; u < 8; ++u) xv[u] = make_float4(0.f, 0.f, 0.f, 0.f);
    }
    ss += __shfl_xor(ss, 1, 64);
    ss += __shfl_xor(ss, 2, 64);
    float inv = 1.f / fmaxf(sqrtf(ss), 1e-12f);
    #pragma unroll
    for (int u = 0; u < 8; ++u) {
        xv[u].x *= inv; xv[u].y *= inv; xv[u].z *= inv; xv[u].w *= inv;
    }
    __syncthreads();
    float pacc[10];
    #pragma unroll
    for (int cc = 0; cc < 10; ++cc) pacc[cc] = 0.f;
    #pragma unroll 1
    for (int c = 0; c < 40; ++c) {
        const float* vrow = &Vs[c][q * 33];
        float acc = 0.f;
        #pragma unroll
        for (int u = 0; u < 8; ++u) {
            acc += xv[u].x * vrow[4 * u]     + xv[u].y * vrow[4 * u + 1]
                 + xv[u].z * vrow[4 * u + 2] + xv[u].w * vrow[4 * u + 3];
        }
        acc += __shfl_xor(acc, 1, 64);
        acc += __shfl_xor(acc, 2, 64);
        if ((c & 3) == q) pacc[c >> 2] = acc;
    }
    if (j < n) {
        #pragma unroll
        for (int cc = 0; cc < 10; ++cc) {
            int c = cc * 4 + q;
            out[(size_t)j * 40 + c] = pacc[cc];
        }
    }
}

// ---------------- launch ----------------

extern "C" void kernel_launch(void* const* d_in, const int* in_sizes, int n_in,
                              void* d_out, int out_size, void* d_ws, size_t ws_size,
                              hipStream_t stream) {
    const float* F    = (const float*)d_in[0];   // (256, 50000)
    const float* W    = (const float*)d_in[1];   // (128, 128)
    const float* Om   = (const float*)d_in[2];   // (128, 256)
    const float* Vw   = (const float*)d_in[3];   // (40, 128)
    const float* X0   = (const float*)d_in[4];   // (128, 50000)
    const float* ew   = (const float*)d_in[5];   // (E,)
    const int*   esrc = (const int*)d_in[6];
    const int*   edst = (const int*)d_in[7];
    float* out = (float*)d_out;
    (void)in_sizes; (void)n_in; (void)out_size; (void)ws_size;

    char* ws = (char*)d_ws;
    size_t off = 0;
    auto alloc = [&](size_t bytes) -> void* {
        void* p = ws + off;
        off = (off + bytes + 255) & ~(size_t)255;
        return p;
    };
    float* buf0    = (float*)alloc((size_t)N_NODES * 4);
    float* buf1    = (float*)alloc((size_t)N_NODES * 4);
    float* ss      = (float*)alloc(64 * 4);
    int*   deg2    = (int*)  alloc((size_t)2 * (N_NODES + 1) * 4);
    int*   offs_s  = (int*)  alloc((size_t)(N_NODES + 1) * 4);
    int*   offs_d  = (int*)  alloc((size_t)(N_NODES + 1) * 4);
    int*   cur_s   = (int*)  alloc((size_t)N_NODES * 4);
    int*   cur_d   = (int*)  alloc((size_t)N_NODES * 4);
    int*   bsum    = (int*)  alloc(512 * 4);
    int*   bbase   = (int*)  alloc(512 * 4);
    int*   csr_dst = (int*)  alloc((size_t)N_EDGES * 4);
    float* csr_ws  = (float*)alloc((size_t)N_EDGES * 4);
    int*   csr_src = (int*)  alloc((size_t)N_EDGES * 4);
    float* csr_wd  = (float*)alloc((size_t)N_EDGES * 4);
    float* Wp      = (float*)alloc(128 * 128 * 4);
    float* WpT     = (float*)alloc(128 * 128 * 4);
    float* OmT     = (float*)alloc(256 * 128 * 4);
    float* bt      = (float*)alloc((size_t)N_NODES * 128 * 4);
    float* Ut      = (float*)alloc((size_t)N_NODES * 128 * 4);
    float* Xa      = (float*)alloc((size_t)N_NODES * 128 * 4);
    float* Xb      = (float*)alloc((size_t)N_NODES * 128 * 4);

    int* deg_s = deg2;
    int* deg_d = deg2 + (N_NODES + 1);

    hipMemsetAsync(deg2, 0, (size_t)2 * (N_NODES + 1) * 4, stream);

    const int n1 = N_NODES + 1;
    const int nb = (n1 + SBLK - 1) / SBLK;   // 196 <= 256

    // ---- CSR builds (both directions) ----
    count_deg_both<<<(N_EDGES + 255) / 256, 256, 0, stream>>>(esrc, edst, deg_s, deg_d, N_EDGES);
    scan_local<<<nb, SBLK, 0, stream>>>(deg_s, offs_s, bsum, n1);
    scan_bsum<<<1, SBLK, 0, stream>>>(bsum, bbase, nb);
    scan_add<<<nb, SBLK, 0, stream>>>(offs_s, cur_s, bbase, n1);
    scan_local<<<nb, SBLK, 0, stream>>>(deg_d, offs_d, bsum, n1);
    scan_bsum<<<1, SBLK, 0, stream>>>(bsum, bbase, nb);
    scan_add<<<nb, SBLK, 0, stream>>>(offs_d, cur_d, bbase, n1);
    fill_csr_both<<<(N_EDGES + 255) / 256, 256, 0, stream>>>(
        esrc, edst, ew, cur_s, csr_dst, csr_ws, cur_d, csr_src, csr_wd, N_EDGES);

    // ---- power iteration: 1 gather-matvec kernel per step ----
    fill_pow<<<(N_NODES + 255) / 256, 256, 0, stream>>>(
        buf0, ss, N_NODES, 1.f / sqrtf((float)N_NODES));
    float* bufs[2] = {buf0, buf1};
    for (int it = 0; it <= PWR_ITERS; ++it) {
        matvec_norm<<<(4 * N_NODES + 255) / 256, 256, 0, stream>>>(
            offs_s, csr_dst, csr_ws, bufs[it & 1], ss + it,
            bufs[(it + 1) & 1], ss + it + 1, N_NODES);
    }

    // ---- project W (rho^2 = ss[PWR_ITERS+1]) ----
    project_w<<<128, 128, 0, stream>>>(W, ss + PWR_ITERS + 1, Wp, WpT);

    // ---- b = (Omega_1 @ U) @ A ----
    transpose_om<<<(128 * 256 + 255) / 256, 256, 0, stream>>>(Om, OmT);
    gemm_u<<<(N_NODES + 63) / 64, 256, 0, stream>>>(F, OmT, Ut, N_NODES);
    spmm_csr<<<(N_NODES + 3) / 4, 256, 0, stream>>>(offs_d, csr_src, csr_wd, Ut, bt, N_NODES);

    // ---- fixed point ----
    transpose_x0<<<dim3((N_NODES + 31) / 32, 4), dim3(32, 8), 0, stream>>>(X0, Xa, N_NODES);
    float* xb2[2] = {Xa, Xb};
    for (int it = 0; it < FP_ITERS; ++it) {
        spmm_csr<<<(N_NODES + 3) / 4, 256, 0, stream>>>(
            offs_d, csr_src, csr_wd, xb2[it & 1], Ut, N_NODES);
        gemm_relu<<<(N_NODES + 63) / 64, 256, 0, stream>>>(
            Ut, WpT, bt, xb2[(it + 1) & 1], N_NODES);
    }

    // ---- output ----
    final_out<<<(N_NODES + 63) / 64, 256, 0, stream>>>(xb2[FP_ITERS & 1], Vw, out, N_NODES);
}

// Round 7
// 2885.624 us; speedup vs baseline: 1.5089x; 1.5089x over previous
//
#include <hip/hip_runtime.h>
#include <math.h>

#define N_NODES 50000
#define N_EDGES 800000
#define M_HID   128
#define P_FEAT  256
#define C_OUT   40
#define PWR_ITERS 50
#define FP_ITERS  30
#define KAPPA 0.9f
#define SBLK 256

typedef unsigned short u16;
typedef unsigned int   u32;
typedef __attribute__((ext_vector_type(8))) short short8;
typedef __attribute__((ext_vector_type(4))) float f32x4;

// bf16 helpers (RNE)
__device__ inline u16 f2bf(float f) {
    union { float f; u32 u; } c; c.f = f;
    u32 u = c.u + 0x7fffu + ((c.u >> 16) & 1u);
    return (u16)(u >> 16);
}
__device__ inline float bflo(u32 u) { union { u32 u; float f; } c; c.u = u << 16; return c.f; }
__device__ inline float bfhi(u32 u) { union { u32 u; float f; } c; c.u = u & 0xffff0000u; return c.f; }

// ---------------- init ----------------

__global__ void fill_pow(float* buf0, float* ss, int n, float val) {
    int i = blockIdx.x * blockDim.x + threadIdx.x;
    if (i < n) buf0[i] = val;
    if (blockIdx.x == 0 && threadIdx.x < 64) ss[threadIdx.x] = (threadIdx.x == 0) ? 1.f : 0.f;
}

// ---------------- power iteration: 4-lane-per-node gather matvec + fused norm ----

__global__ __launch_bounds__(256) void matvec_norm(const int* __restrict__ offs,
                                                   const int2* __restrict__ csr,
                                                   const float* __restrict__ vin,
                                                   const float* __restrict__ n2in,
                                                   float* __restrict__ vout,
                                                   float* n2out, int n) {
    int t = blockIdx.x * blockDim.x + threadIdx.x;
    int g = t >> 2, q = t & 3;
    float inv = 1.f / (sqrtf(*n2in) + 1e-12f);
    float a = 0.f;
    if (g < n) {
        int lo = offs[g], hi = offs[g + 1];
        for (int e = lo + q; e < hi; e += 4) {
            int2 c = csr[e];
            a += __int_as_float(c.y) * vin[c.x];
        }
    }
    a += __shfl_xor(a, 1, 64);
    a += __shfl_xor(a, 2, 64);
    a *= inv;
    if (g < n && q == 0) vout[g] = a;
    float s = (q == 0 && g < n) ? a * a : 0.f;
    for (int o = 32; o > 0; o >>= 1) s += __shfl_down(s, o, 64);
    __shared__ float ls[4];
    int lane = threadIdx.x & 63, wid = threadIdx.x >> 6;
    if (lane == 0) ls[wid] = s;
    __syncthreads();
    if (threadIdx.x == 0) atomicAdd(n2out, ls[0] + ls[1] + ls[2] + ls[3]);
}

// ---------------- L1-ball row projection of W -> MFMA B-fragment layout ----------------
// Bswz flat layout: [kf 0..3][nt 0..7][lane 0..63][j 0..7] bf16, where the MFMA
// B-operand element for lane l, reg j at (kf,nt) is WpT[kf*32+(l>>4)*8+j][nt*16+(l&15)]
//  = Wp[nt*16+(l&15)][kf*32+(l>>4)*8+j].

__global__ __launch_bounds__(128) void project_w(const float* __restrict__ W,
                                                 const float* __restrict__ rho2,
                                                 u16* __restrict__ Bswz) {
    __shared__ float sa[128];
    __shared__ float ssort[128];
    __shared__ float sc[128];
    __shared__ int cnt2[2];
    int r = blockIdx.x, t = threadIdx.x;
    float radius = KAPPA / sqrtf(*rho2);
    float w0 = W[r * 128 + t];
    float a = fabsf(w0);
    sa[t] = a;
    __syncthreads();
    int rank = 0;
    #pragma unroll 8
    for (int j = 0; j < 128; ++j) {
        float aj = sa[j];
        rank += (aj > a) || (aj == a && j < t);
    }
    ssort[rank] = a;
    __syncthreads();
    sc[t] = ssort[t];
    __syncthreads();
    for (int off = 1; off < 128; off <<= 1) {
        float add = (t >= off) ? sc[t - off] : 0.f;
        __syncthreads();
        sc[t] += add;
        __syncthreads();
    }
    bool flag = ssort[t] * (float)(t + 1) > sc[t] - radius;
    unsigned long long b = __ballot(flag);
    if ((t & 63) == 0) cnt2[t >> 6] = __popcll(b);
    __syncthreads();
    int rho = cnt2[0] + cnt2[1];
    float total = sc[127];
    bool needs = total > radius;
    float theta = (sc[rho - 1] - radius) / (float)rho;
    float o;
    if (needs) {
        float am = a - theta;
        o = (am > 0.f) ? ((w0 > 0.f) ? am : -am) : 0.f;
    } else o = w0;
    // scatter into B-fragment layout
    int kf = t >> 5, quad = (t >> 3) & 3, jj = t & 7;
    int nt = r >> 4, li = r & 15;
    int l = quad * 16 + li;
    Bswz[((size_t)(kf * 8 + nt) * 64 + l) * 8 + jj] = f2bf(o);
}

// ---------------- CSR builds (by src AND by dst), int2-packed ----------------

__global__ void count_deg_both(const int* __restrict__ src, const int* __restrict__ dst,
                               int* deg_s, int* deg_d, int E) {
    int e = blockIdx.x * blockDim.x + threadIdx.x;
    if (e < E) {
        atomicAdd(&deg_s[src[e]], 1);
        atomicAdd(&deg_d[dst[e]], 1);
    }
}

__global__ __launch_bounds__(SBLK) void scan_local(const int* __restrict__ deg,
                                                   int* __restrict__ offsets,
                                                   int* __restrict__ bsum, int n1) {
    __shared__ int s[SBLK];
    int i = blockIdx.x * SBLK + threadIdx.x;
    int v = (i < n1 - 1) ? deg[i] : 0;
    s[threadIdx.x] = v;
    __syncthreads();
    for (int o = 1; o < SBLK; o <<= 1) {
        int add = (threadIdx.x >= o) ? s[threadIdx.x - o] : 0;
        __syncthreads();
        s[threadIdx.x] += add;
        __syncthreads();
    }
    if (i < n1) offsets[i] = s[threadIdx.x] - v;   // exclusive
    if (threadIdx.x == SBLK - 1) bsum[blockIdx.x] = s[SBLK - 1];
}

__global__ __launch_bounds__(SBLK) void scan_bsum(const int* __restrict__ bsum,
                                                  int* __restrict__ bbase, int nb) {
    __shared__ int s[SBLK];
    int v = (threadIdx.x < nb) ? bsum[threadIdx.x] : 0;
    s[threadIdx.x] = v;
    __syncthreads();
    for (int o = 1; o < SBLK; o <<= 1) {
        int add = (threadIdx.x >= o) ? s[threadIdx.x - o] : 0;
        __syncthreads();
        s[threadIdx.x] += add;
        __syncthreads();
    }
    if (threadIdx.x < nb) bbase[threadIdx.x] = s[threadIdx.x] - v;
}

__global__ __launch_bounds__(SBLK) void scan_add(int* __restrict__ offsets,
                                                 int* __restrict__ cursor,
                                                 const int* __restrict__ bbase, int n1) {
    int i = blockIdx.x * SBLK + threadIdx.x;
    if (i < n1) {
        int o = offsets[i] + bbase[blockIdx.x];
        offsets[i] = o;
        if (i < n1 - 1) cursor[i] = o;
    }
}

__global__ void fill_csr_both(const int* __restrict__ src, const int* __restrict__ dst,
                              const float* __restrict__ w,
                              int* cur_s, int2* csr_s,
                              int* cur_d, int2* csr_d, int E) {
    int e = blockIdx.x * blockDim.x + threadIdx.x;
    if (e < E) {
        int s = src[e], d = dst[e];
        int wb = __float_as_int(w[e]);
        int ps = atomicAdd(&cur_s[s], 1);
        csr_s[ps] = make_int2(d, wb);
        int pd = atomicAdd(&cur_d[d], 1);
        csr_d[pd] = make_int2(s, wb);
    }
}

// ---------------- small transposes ----------------

__global__ void transpose_om(const float* __restrict__ Om, float* OmT) {
    int idx = blockIdx.x * blockDim.x + threadIdx.x;
    if (idx < 128 * 256) {
        int t = idx / 256, k = idx % 256;
        OmT[k * 128 + t] = Om[idx];
    }
}

__global__ void transpose_x0_bf16(const float* __restrict__ X0, u16* Xb, int n) {
    __shared__ float tile[32][33];
    int jb = blockIdx.x * 32, tb = blockIdx.y * 32;
    int tx = threadIdx.x, ty = threadIdx.y;
    for (int r = 0; r < 32; r += 8) {
        int t = tb + ty + r, j = jb + tx;
        tile[ty + r][tx] = (j < n) ? X0[(size_t)t * n + j] : 0.f;
    }
    __syncthreads();
    for (int r = 0; r < 32; r += 8) {
        int j = jb + ty + r, t = tb + tx;
        if (j < n) Xb[(size_t)j * 128 + t] = f2bf(tile[tx][ty + r]);
    }
}

// ---------------- one-shot dense GEMM: Ut = F^T @ OmT (f32, 64-row tiles) ----------

__global__ __launch_bounds__(256) void gemm_u(const float* __restrict__ F,
                                              const float* __restrict__ OmT,
                                              float* __restrict__ C, int n) {
    __shared__ float Fs[16][65];
    __shared__ float Bs[16][129];
    int j0 = blockIdx.x * 64;
    int tid = threadIdx.x;
    int tj = tid >> 4, tg = tid & 15;
    float acc[4][8] = {};
    for (int k0 = 0; k0 < 256; k0 += 16) {
        #pragma unroll
        for (int r = 0; r < 4; ++r) {
            int idx = r * 256 + tid;
            int kk = idx >> 6, jj = idx & 63;
            int j = j0 + jj;
            Fs[kk][jj] = (j < n) ? F[(size_t)(k0 + kk) * n + j] : 0.f;
        }
        #pragma unroll
        for (int r = 0; r < 8; ++r) {
            int idx = r * 256 + tid;
            int kk = idx >> 7, tt = idx & 127;
            Bs[kk][tt] = OmT[(k0 + kk) * 128 + tt];
        }
        __syncthreads();
        #pragma unroll
        for (int kk = 0; kk < 16; ++kk) {
            float a[4], b[8];
            #pragma unroll
            for (int u = 0; u < 4; ++u) a[u] = Fs[kk][tj + 16 * u];
            #pragma unroll
            for (int u = 0; u < 8; ++u) b[u] = Bs[kk][tg + 16 * u];
            #pragma unroll
            for (int x = 0; x < 4; ++x)
                #pragma unroll
                for (int y = 0; y < 8; ++y)
                    acc[x][y] += a[x] * b[y];
        }
        __syncthreads();
    }
    #pragma unroll
    for (int x = 0; x < 4; ++x) {
        int j = j0 + tj + 16 * x;
        if (j < n)
            #pragma unroll
            for (int y = 0; y < 8; ++y)
                C[(size_t)j * 128 + tg + 16 * y] = acc[x][y];
    }
}

// ---------------- spmm f32 (for bias b), int2 CSR ----------------

__global__ __launch_bounds__(256) void spmm_f32(const int* __restrict__ offsets,
                                                const int2* __restrict__ csr,
                                                const float* __restrict__ Xin,
                                                float* __restrict__ Yout, int n) {
    int j = blockIdx.x * 4 + (threadIdx.x >> 6);
    if (j >= n) return;
    int lane = threadIdx.x & 63;
    int lo = offsets[j], hi = offsets[j + 1];
    const float2* __restrict__ X2 = (const float2*)Xin;
    float2 acc = {0.f, 0.f};
    int e = lo;
    for (; e + 8 <= hi; e += 8) {
        int2 c[8];
        #pragma unroll
        for (int u = 0; u < 8; ++u) c[u] = csr[e + u];
        float2 x[8];
        #pragma unroll
        for (int u = 0; u < 8; ++u) x[u] = X2[(size_t)c[u].x * 64 + lane];
        #pragma unroll
        for (int u = 0; u < 8; ++u) {
            float w = __int_as_float(c[u].y);
            acc.x += w * x[u].x;
            acc.y += w * x[u].y;
        }
    }
    for (; e < hi; ++e) {
        int2 c = csr[e];
        float w = __int_as_float(c.y);
        float2 x = X2[(size_t)c.x * 64 + lane];
        acc.x += w * x.x;
        acc.y += w * x.y;
    }
    ((float2*)Yout)[(size_t)j * 64 + lane] = acc;
}

// ---------------- spmm bf16 (FP loop): Y = X @ A ----------------

__global__ __launch_bounds__(256) void spmm_bf16(const int* __restrict__ offsets,
                                                 const int2* __restrict__ csr,
                                                 const u16* __restrict__ Xin,
                                                 u16* __restrict__ Yout, int n) {
    int j = blockIdx.x * 4 + (threadIdx.x >> 6);
    if (j >= n) return;
    int lane = threadIdx.x & 63;
    int lo = offsets[j], hi = offsets[j + 1];
    const u32* __restrict__ X1 = (const u32*)Xin;
    float ax = 0.f, ay = 0.f;
    int e = lo;
    for (; e + 8 <= hi; e += 8) {
        int2 c[8];
        #pragma unroll
        for (int u = 0; u < 8; ++u) c[u] = csr[e + u];
        u32 x[8];
        #pragma unroll
        for (int u = 0; u < 8; ++u) x[u] = X1[(size_t)c[u].x * 64 + lane];
        #pragma unroll
        for (int u = 0; u < 8; ++u) {
            float w = __int_as_float(c[u].y);
            ax += w * bflo(x[u]);
            ay += w * bfhi(x[u]);
        }
    }
    for (; e < hi; ++e) {
        int2 c = csr[e];
        float w = __int_as_float(c.y);
        u32 x = X1[(size_t)c.x * 64 + lane];
        ax += w * bflo(x);
        ay += w * bfhi(x);
    }
    ((u32*)Yout)[(size_t)j * 64 + lane] = (u32)f2bf(ax) | ((u32)f2bf(ay) << 16);
}

// ---------------- gemm_relu via MFMA: X = relu(Y @ WpT + bt) ----------------
// 256 thr = 4 waves; block = 64 rows; wave w owns rows j0+w*16 .. +15.
// No LDS, no barriers: A-frags read 16B/lane from Y; B-frags from Bswz.

__global__ __launch_bounds__(256) void gemm_relu_mfma(const u16* __restrict__ Yb,
                                                      const u16* __restrict__ Bswz,
                                                      const float* __restrict__ bt,
                                                      u16* __restrict__ Xb, int n) {
    int tid = threadIdx.x;
    int w = tid >> 6, l = tid & 63;
    int j0 = blockIdx.x * 64 + w * 16;
    int row_a = j0 + (l & 15);
    bool rowa_ok = row_a < n;
    const short8* __restrict__ yrow = (const short8*)(Yb + (size_t)row_a * 128);
    const short8* __restrict__ bfr = (const short8*)Bswz;
    f32x4 acc[8];
    #pragma unroll
    for (int nt = 0; nt < 8; ++nt) acc[nt] = (f32x4){0.f, 0.f, 0.f, 0.f};
    #pragma unroll
    for (int kf = 0; kf < 4; ++kf) {
        short8 a = {0, 0, 0, 0, 0, 0, 0, 0};
        if (rowa_ok) a = yrow[kf * 4 + (l >> 4)];
        #pragma unroll
        for (int nt = 0; nt < 8; ++nt) {
            short8 b = bfr[(kf * 8 + nt) * 64 + l];
            acc[nt] = __builtin_amdgcn_mfma_f32_16x16x32_bf16(a, b, acc[nt], 0, 0, 0);
        }
    }
    int rbase = j0 + (l >> 4) * 4;
    int cbase = l & 15;
    #pragma unroll
    for (int nt = 0; nt < 8; ++nt) {
        int col = nt * 16 + cbase;
        #pragma unroll
        for (int i = 0; i < 4; ++i) {
            int row = rbase + i;
            if (row < n) {
                float v = acc[nt][i] + bt[(size_t)row * 128 + col];
                Xb[(size_t)row * 128 + col] = f2bf(v > 0.f ? v : 0.f);
            }
        }
    }
}

// ---------------- final: normalize rows + H @ Vw^T (bf16 input) ----------------

__global__ __launch_bounds__(256) void final_out(const u16* __restrict__ Xb,
                                                 const float* __restrict__ Vw,
                                                 float* __restrict__ out, int n) {
    __shared__ float Vs[40][132];
    int tid = threadIdx.x;
    int jb = blockIdx.x * 64;
    for (int i = tid; i < 40 * 128; i += 256) {
        int c = i >> 7, k = i & 127;
        Vs[c][(k >> 5) * 33 + (k & 31)] = Vw[i];
    }
    int g = tid >> 2, q = tid & 3;
    int j = jb + g;
    float xs[32];
    float ssq = 0.f;
    if (j < n) {
        const uint4* X4 = (const uint4*)(Xb + (size_t)j * 128) + q * 4;
        #pragma unroll
        for (int v = 0; v < 4; ++v) {
            uint4 u = X4[v];
            xs[v * 8 + 0] = bflo(u.x); xs[v * 8 + 1] = bfhi(u.x);
            xs[v * 8 + 2] = bflo(u.y); xs[v * 8 + 3] = bfhi(u.y);
            xs[v * 8 + 4] = bflo(u.z); xs[v * 8 + 5] = bfhi(u.z);
            xs[v * 8 + 6] = bflo(u.w); xs[v * 8 + 7] = bfhi(u.w);
        }
        #pragma unroll
        for (int m = 0; m < 32; ++m) ssq += xs[m] * xs[m];
    } else {
        #pragma unroll
        for (int m = 0; m < 32; ++m) xs[m] = 0.f;
    }
    ssq += __shfl_xor(ssq, 1, 64);
    ssq += __shfl_xor(ssq, 2, 64);
    float inv = 1.f / fmaxf(sqrtf(ssq), 1e-12f);
    #pragma unroll
    for (int m = 0; m < 32; ++m) xs[m] *= inv;
    __syncthreads();
    float pacc[10];
    #pragma unroll
    for (int cc = 0; cc < 10; ++cc) pacc[cc] = 0.f;
    #pragma unroll 1
    for (int c = 0; c < 40; ++c) {
        const float* vrow = &Vs[c][q * 33];
        float acc = 0.f;
        #pragma unroll
        for (int m = 0; m < 32; ++m) acc += xs[m] * vrow[m];
        acc += __shfl_xor(acc, 1, 64);
        acc += __shfl_xor(acc, 2, 64);
        if ((c & 3) == q) pacc[c >> 2] = acc;
    }
    if (j < n) {
        #pragma unroll
        for (int cc = 0; cc < 10; ++cc) {
            int c = cc * 4 + q;
            out[(size_t)j * 40 + c] = pacc[cc];
        }
    }
}

// ---------------- launch ----------------

extern "C" void kernel_launch(void* const* d_in, const int* in_sizes, int n_in,
                              void* d_out, int out_size, void* d_ws, size_t ws_size,
                              hipStream_t stream) {
    const float* F    = (const float*)d_in[0];   // (256, 50000)
    const float* W    = (const float*)d_in[1];   // (128, 128)
    const float* Om   = (const float*)d_in[2];   // (128, 256)
    const float* Vw   = (const float*)d_in[3];   // (40, 128)
    const float* X0   = (const float*)d_in[4];   // (128, 50000)
    const float* ew   = (const float*)d_in[5];   // (E,)
    const int*   esrc = (const int*)d_in[6];
    const int*   edst = (const int*)d_in[7];
    float* out = (float*)d_out;
    (void)in_sizes; (void)n_in; (void)out_size; (void)ws_size;

    char* ws = (char*)d_ws;
    size_t off = 0;
    auto alloc = [&](size_t bytes) -> void* {
        void* p = ws + off;
        off = (off + bytes + 255) & ~(size_t)255;
        return p;
    };
    float* buf0    = (float*)alloc((size_t)N_NODES * 4);
    float* buf1    = (float*)alloc((size_t)N_NODES * 4);
    float* ss      = (float*)alloc(64 * 4);
    int*   deg2    = (int*)  alloc((size_t)2 * (N_NODES + 1) * 4);
    int*   offs_s  = (int*)  alloc((size_t)(N_NODES + 1) * 4);
    int*   offs_d  = (int*)  alloc((size_t)(N_NODES + 1) * 4);
    int*   cur_s   = (int*)  alloc((size_t)N_NODES * 4);
    int*   cur_d   = (int*)  alloc((size_t)N_NODES * 4);
    int*   bsum    = (int*)  alloc(512 * 4);
    int*   bbase   = (int*)  alloc(512 * 4);
    int2*  csr_s   = (int2*) alloc((size_t)N_EDGES * 8);   // by-src: (dst, w)
    int2*  csr_d   = (int2*) alloc((size_t)N_EDGES * 8);   // by-dst: (src, w)
    u16*   Bswz    = (u16*)  alloc(128 * 128 * 2);
    float* OmT     = (float*)alloc(256 * 128 * 4);
    float* bt      = (float*)alloc((size_t)N_NODES * 128 * 4);
    float* Ut      = (float*)alloc((size_t)N_NODES * 128 * 4);
    u16*   Yb      = (u16*)  alloc((size_t)N_NODES * 128 * 2);
    u16*   Xa      = (u16*)  alloc((size_t)N_NODES * 128 * 2);
    u16*   Xb      = (u16*)  alloc((size_t)N_NODES * 128 * 2);

    int* deg_s = deg2;
    int* deg_d = deg2 + (N_NODES + 1);

    hipMemsetAsync(deg2, 0, (size_t)2 * (N_NODES + 1) * 4, stream);

    const int n1 = N_NODES + 1;
    const int nb = (n1 + SBLK - 1) / SBLK;   // 196 <= 256

    // ---- CSR builds (both directions) ----
    count_deg_both<<<(N_EDGES + 255) / 256, 256, 0, stream>>>(esrc, edst, deg_s, deg_d, N_EDGES);
    scan_local<<<nb, SBLK, 0, stream>>>(deg_s, offs_s, bsum, n1);
    scan_bsum<<<1, SBLK, 0, stream>>>(bsum, bbase, nb);
    scan_add<<<nb, SBLK, 0, stream>>>(offs_s, cur_s, bbase, n1);
    scan_local<<<nb, SBLK, 0, stream>>>(deg_d, offs_d, bsum, n1);
    scan_bsum<<<1, SBLK, 0, stream>>>(bsum, bbase, nb);
    scan_add<<<nb, SBLK, 0, stream>>>(offs_d, cur_d, bbase, n1);
    fill_csr_both<<<(N_EDGES + 255) / 256, 256, 0, stream>>>(
        esrc, edst, ew, cur_s, csr_s, cur_d, csr_d, N_EDGES);

    // ---- power iteration: 1 gather-matvec kernel per step ----
    fill_pow<<<(N_NODES + 255) / 256, 256, 0, stream>>>(
        buf0, ss, N_NODES, 1.f / sqrtf((float)N_NODES));
    float* bufs[2] = {buf0, buf1};
    for (int it = 0; it <= PWR_ITERS; ++it) {
        matvec_norm<<<(4 * N_NODES + 255) / 256, 256, 0, stream>>>(
            offs_s, csr_s, bufs[it & 1], ss + it,
            bufs[(it + 1) & 1], ss + it + 1, N_NODES);
    }

    // ---- project W (rho^2 = ss[PWR_ITERS+1]) -> Bswz fragments ----
    project_w<<<128, 128, 0, stream>>>(W, ss + PWR_ITERS + 1, Bswz);

    // ---- b = (Omega_1 @ U) @ A  (f32) ----
    transpose_om<<<(128 * 256 + 255) / 256, 256, 0, stream>>>(Om, OmT);
    gemm_u<<<(N_NODES + 63) / 64, 256, 0, stream>>>(F, OmT, Ut, N_NODES);
    spmm_f32<<<(N_NODES + 3) / 4, 256, 0, stream>>>(offs_d, csr_d, Ut, bt, N_NODES);

    // ---- fixed point (bf16 X/Y, MFMA gemm) ----
    transpose_x0_bf16<<<dim3((N_NODES + 31) / 32, 4), dim3(32, 8), 0, stream>>>(X0, Xa, N_NODES);
    u16* xb2[2] = {Xa, Xb};
    for (int it = 0; it < FP_ITERS; ++it) {
        spmm_bf16<<<(N_NODES + 3) / 4, 256, 0, stream>>>(
            offs_d, csr_d, xb2[it & 1], Yb, N_NODES);
        gemm_relu_mfma<<<(N_NODES + 63) / 64, 256, 0, stream>>>(
            Yb, Bswz, bt, xb2[(it + 1) & 1], N_NODES);
    }

    // ---- output ----
    final_out<<<(N_NODES + 63) / 64, 256, 0, stream>>>(xb2[FP_ITERS & 1], Vw, out, N_NODES);
}

// Round 8
// 2868.368 us; speedup vs baseline: 1.5180x; 1.0060x over previous
//
#include <hip/hip_runtime.h>
#include <math.h>

#define N_NODES 50000
#define N_EDGES 800000
#define M_HID   128
#define P_FEAT  256
#define C_OUT   40
#define PWR_ITERS 50
#define FP_ITERS  30
#define KAPPA 0.9f
#define SBLK 256

typedef unsigned short u16;
typedef unsigned int   u32;
typedef __attribute__((ext_vector_type(8))) short short8;
typedef __attribute__((ext_vector_type(4))) float f32x4;

// bf16 helpers (RNE)
__device__ inline u16 f2bf(float f) {
    union { float f; u32 u; } c; c.f = f;
    u32 u = c.u + 0x7fffu + ((c.u >> 16) & 1u);
    return (u16)(u >> 16);
}
__device__ inline float bf2f(u16 h) { union { u32 u; float f; } c; c.u = (u32)h << 16; return c.f; }
__device__ inline float bflo(u32 u) { union { u32 u; float f; } c; c.u = u << 16; return c.f; }
__device__ inline float bfhi(u32 u) { union { u32 u; float f; } c; c.u = u & 0xffff0000u; return c.f; }

// ---------------- init ----------------

__global__ void fill_pow(float* buf0, float* ss, int n, float val) {
    int i = blockIdx.x * blockDim.x + threadIdx.x;
    if (i < n) buf0[i] = val;
    if (blockIdx.x == 0 && threadIdx.x < 64) ss[threadIdx.x] = (threadIdx.x == 0) ? 1.f : 0.f;
}

// ---------------- power iteration on A^T (same spectral radius): 4-lane/node ----

__global__ __launch_bounds__(256) void matvec_norm(const int* __restrict__ offs,
                                                   const int2* __restrict__ csr,
                                                   const float* __restrict__ vin,
                                                   const float* __restrict__ n2in,
                                                   float* __restrict__ vout,
                                                   float* n2out, int n) {
    int t = blockIdx.x * blockDim.x + threadIdx.x;
    int g = t >> 2, q = t & 3;
    float inv = 1.f / (sqrtf(*n2in) + 1e-12f);
    float a = 0.f;
    if (g < n) {
        int lo = offs[g], hi = offs[g + 1];
        for (int e = lo + q; e < hi; e += 4) {
            int2 c = csr[e];
            a += __int_as_float(c.y) * vin[c.x];
        }
    }
    a += __shfl_xor(a, 1, 64);
    a += __shfl_xor(a, 2, 64);
    a *= inv;
    if (g < n && q == 0) vout[g] = a;
    float s = (q == 0 && g < n) ? a * a : 0.f;
    for (int o = 32; o > 0; o >>= 1) s += __shfl_down(s, o, 64);
    __shared__ float ls[4];
    int lane = threadIdx.x & 63, wid = threadIdx.x >> 6;
    if (lane == 0) ls[wid] = s;
    __syncthreads();
    if (threadIdx.x == 0) atomicAdd(n2out, ls[0] + ls[1] + ls[2] + ls[3]);
}

// ---------------- L1-ball row projection of W -> MFMA B-fragment layout ----------------

__global__ __launch_bounds__(128) void project_w(const float* __restrict__ W,
                                                 const float* __restrict__ rho2,
                                                 u16* __restrict__ Bswz) {
    __shared__ float sa[128];
    __shared__ float ssort[128];
    __shared__ float sc[128];
    __shared__ int cnt2[2];
    int r = blockIdx.x, t = threadIdx.x;
    float radius = KAPPA / sqrtf(*rho2);
    float w0 = W[r * 128 + t];
    float a = fabsf(w0);
    sa[t] = a;
    __syncthreads();
    int rank = 0;
    #pragma unroll 8
    for (int j = 0; j < 128; ++j) {
        float aj = sa[j];
        rank += (aj > a) || (aj == a && j < t);
    }
    ssort[rank] = a;
    __syncthreads();
    sc[t] = ssort[t];
    __syncthreads();
    for (int off = 1; off < 128; off <<= 1) {
        float add = (t >= off) ? sc[t - off] : 0.f;
        __syncthreads();
        sc[t] += add;
        __syncthreads();
    }
    bool flag = ssort[t] * (float)(t + 1) > sc[t] - radius;
    unsigned long long b = __ballot(flag);
    if ((t & 63) == 0) cnt2[t >> 6] = __popcll(b);
    __syncthreads();
    int rho = cnt2[0] + cnt2[1];
    float total = sc[127];
    bool needs = total > radius;
    float theta = (sc[rho - 1] - radius) / (float)rho;
    float o;
    if (needs) {
        float am = a - theta;
        o = (am > 0.f) ? ((w0 > 0.f) ? am : -am) : 0.f;
    } else o = w0;
    // scatter into B-fragment layout
    int kf = t >> 5, quad = (t >> 3) & 3, jj = t & 7;
    int nt = r >> 4, li = r & 15;
    int l = quad * 16 + li;
    Bswz[((size_t)(kf * 8 + nt) * 64 + l) * 8 + jj] = f2bf(o);
}

// ---------------- CSR build (by dst only), int2-packed ----------------

__global__ void count_deg(const int* __restrict__ dst, int* deg, int E) {
    int e = blockIdx.x * blockDim.x + threadIdx.x;
    if (e < E) atomicAdd(&deg[dst[e]], 1);
}

__global__ __launch_bounds__(SBLK) void scan_local(const int* __restrict__ deg,
                                                   int* __restrict__ offsets,
                                                   int* __restrict__ bsum, int n1) {
    __shared__ int s[SBLK];
    int i = blockIdx.x * SBLK + threadIdx.x;
    int v = (i < n1 - 1) ? deg[i] : 0;
    s[threadIdx.x] = v;
    __syncthreads();
    for (int o = 1; o < SBLK; o <<= 1) {
        int add = (threadIdx.x >= o) ? s[threadIdx.x - o] : 0;
        __syncthreads();
        s[threadIdx.x] += add;
        __syncthreads();
    }
    if (i < n1) offsets[i] = s[threadIdx.x] - v;   // exclusive
    if (threadIdx.x == SBLK - 1) bsum[blockIdx.x] = s[SBLK - 1];
}

__global__ __launch_bounds__(SBLK) void scan_bsum(const int* __restrict__ bsum,
                                                  int* __restrict__ bbase, int nb) {
    __shared__ int s[SBLK];
    int v = (threadIdx.x < nb) ? bsum[threadIdx.x] : 0;
    s[threadIdx.x] = v;
    __syncthreads();
    for (int o = 1; o < SBLK; o <<= 1) {
        int add = (threadIdx.x >= o) ? s[threadIdx.x - o] : 0;
        __syncthreads();
        s[threadIdx.x] += add;
        __syncthreads();
    }
    if (threadIdx.x < nb) bbase[threadIdx.x] = s[threadIdx.x] - v;
}

__global__ __launch_bounds__(SBLK) void scan_add(int* __restrict__ offsets,
                                                 int* __restrict__ cursor,
                                                 const int* __restrict__ bbase, int n1) {
    int i = blockIdx.x * SBLK + threadIdx.x;
    if (i < n1) {
        int o = offsets[i] + bbase[blockIdx.x];
        offsets[i] = o;
        if (i < n1 - 1) cursor[i] = o;
    }
}

__global__ void fill_csr(const int* __restrict__ src, const int* __restrict__ dst,
                         const float* __restrict__ w,
                         int* cur_d, int2* csr_d, int E) {
    int e = blockIdx.x * blockDim.x + threadIdx.x;
    if (e < E) {
        int d = dst[e];
        int pd = atomicAdd(&cur_d[d], 1);
        csr_d[pd] = make_int2(src[e], __float_as_int(w[e]));
    }
}

// ---------------- small transposes ----------------

__global__ void transpose_om(const float* __restrict__ Om, float* OmT) {
    int idx = blockIdx.x * blockDim.x + threadIdx.x;
    if (idx < 128 * 256) {
        int t = idx / 256, k = idx % 256;
        OmT[k * 128 + t] = Om[idx];
    }
}

__global__ void transpose_x0_bf16(const float* __restrict__ X0, u16* Xb, int n) {
    __shared__ float tile[32][33];
    int jb = blockIdx.x * 32, tb = blockIdx.y * 32;
    int tx = threadIdx.x, ty = threadIdx.y;
    for (int r = 0; r < 32; r += 8) {
        int t = tb + ty + r, j = jb + tx;
        tile[ty + r][tx] = (j < n) ? X0[(size_t)t * n + j] : 0.f;
    }
    __syncthreads();
    for (int r = 0; r < 32; r += 8) {
        int j = jb + ty + r, t = tb + tx;
        if (j < n) Xb[(size_t)j * 128 + t] = f2bf(tile[tx][ty + r]);
    }
}

// ---------------- one-shot dense GEMM: Ut = F^T @ OmT (f32, 64-row tiles) ----------

__global__ __launch_bounds__(256) void gemm_u(const float* __restrict__ F,
                                              const float* __restrict__ OmT,
                                              float* __restrict__ C, int n) {
    __shared__ float Fs[16][65];
    __shared__ float Bs[16][129];
    int j0 = blockIdx.x * 64;
    int tid = threadIdx.x;
    int tj = tid >> 4, tg = tid & 15;
    float acc[4][8] = {};
    for (int k0 = 0; k0 < 256; k0 += 16) {
        #pragma unroll
        for (int r = 0; r < 4; ++r) {
            int idx = r * 256 + tid;
            int kk = idx >> 6, jj = idx & 63;
            int j = j0 + jj;
            Fs[kk][jj] = (j < n) ? F[(size_t)(k0 + kk) * n + j] : 0.f;
        }
        #pragma unroll
        for (int r = 0; r < 8; ++r) {
            int idx = r * 256 + tid;
            int kk = idx >> 7, tt = idx & 127;
            Bs[kk][tt] = OmT[(k0 + kk) * 128 + tt];
        }
        __syncthreads();
        #pragma unroll
        for (int kk = 0; kk < 16; ++kk) {
            float a[4], b[8];
            #pragma unroll
            for (int u = 0; u < 4; ++u) a[u] = Fs[kk][tj + 16 * u];
            #pragma unroll
            for (int u = 0; u < 8; ++u) b[u] = Bs[kk][tg + 16 * u];
            #pragma unroll
            for (int x = 0; x < 4; ++x)
                #pragma unroll
                for (int y = 0; y < 8; ++y)
                    acc[x][y] += a[x] * b[y];
        }
        __syncthreads();
    }
    #pragma unroll
    for (int x = 0; x < 4; ++x) {
        int j = j0 + tj + 16 * x;
        if (j < n)
            #pragma unroll
            for (int y = 0; y < 8; ++y)
                C[(size_t)j * 128 + tg + 16 * y] = acc[x][y];
    }
}

// ---------------- spmm f32 -> bf16 bias: bt = (U @ A) as bf16 ----------------

__global__ __launch_bounds__(256) void spmm_f32(const int* __restrict__ offsets,
                                                const int2* __restrict__ csr,
                                                const float* __restrict__ Xin,
                                                u16* __restrict__ Yout, int n) {
    int j = blockIdx.x * 4 + (threadIdx.x >> 6);
    if (j >= n) return;
    int lane = threadIdx.x & 63;
    int lo = offsets[j], hi = offsets[j + 1];
    const float2* __restrict__ X2 = (const float2*)Xin;
    float2 acc = {0.f, 0.f};
    int e = lo;
    for (; e + 8 <= hi; e += 8) {
        int2 c[8];
        #pragma unroll
        for (int u = 0; u < 8; ++u) c[u] = csr[e + u];
        float2 x[8];
        #pragma unroll
        for (int u = 0; u < 8; ++u) x[u] = X2[(size_t)c[u].x * 64 + lane];
        #pragma unroll
        for (int u = 0; u < 8; ++u) {
            float w = __int_as_float(c[u].y);
            acc.x += w * x[u].x;
            acc.y += w * x[u].y;
        }
    }
    for (; e < hi; ++e) {
        int2 c = csr[e];
        float w = __int_as_float(c.y);
        float2 x = X2[(size_t)c.x * 64 + lane];
        acc.x += w * x.x;
        acc.y += w * x.y;
    }
    ((u32*)Yout)[(size_t)j * 64 + lane] = (u32)f2bf(acc.x) | ((u32)f2bf(acc.y) << 16);
}

// ---------------- spmm bf16 (FP loop): Y = X @ A, uint2 gathers ----------------
// Wave per dst row; lanes 0-31 even edges, 32-63 odd edges; each lane covers 4 cols.

__global__ __launch_bounds__(256) void spmm_bf16(const int* __restrict__ offsets,
                                                 const int2* __restrict__ csr,
                                                 const u16* __restrict__ Xin,
                                                 u16* __restrict__ Yout, int n) {
    int j = blockIdx.x * 4 + (threadIdx.x >> 6);
    if (j >= n) return;
    int lane = threadIdx.x & 63;
    int half = lane >> 5, li = lane & 31;
    int lo = offsets[j], hi = offsets[j + 1];
    const uint2* __restrict__ X2 = (const uint2*)Xin;   // 32 x 8B per row
    float a0 = 0.f, a1 = 0.f, a2 = 0.f, a3 = 0.f;
    int e = lo + half;
    for (; e + 14 < hi; e += 16) {        // 8 edges per half per round
        int2 c[8];
        #pragma unroll
        for (int u = 0; u < 8; ++u) c[u] = csr[e + 2 * u];
        uint2 x[8];
        #pragma unroll
        for (int u = 0; u < 8; ++u) x[u] = X2[(size_t)c[u].x * 32 + li];
        #pragma unroll
        for (int u = 0; u < 8; ++u) {
            float w = __int_as_float(c[u].y);
            a0 += w * bflo(x[u].x); a1 += w * bfhi(x[u].x);
            a2 += w * bflo(x[u].y); a3 += w * bfhi(x[u].y);
        }
    }
    for (; e < hi; e += 2) {
        int2 c = csr[e];
        uint2 x = X2[(size_t)c.x * 32 + li];
        float w = __int_as_float(c.y);
        a0 += w * bflo(x.x); a1 += w * bfhi(x.x);
        a2 += w * bflo(x.y); a3 += w * bfhi(x.y);
    }
    a0 += __shfl_xor(a0, 32, 64);
    a1 += __shfl_xor(a1, 32, 64);
    a2 += __shfl_xor(a2, 32, 64);
    a3 += __shfl_xor(a3, 32, 64);
    if (half == 0) {
        uint2 o;
        o.x = (u32)f2bf(a0) | ((u32)f2bf(a1) << 16);
        o.y = (u32)f2bf(a2) | ((u32)f2bf(a3) << 16);
        ((uint2*)Yout)[(size_t)j * 32 + li] = o;
    }
}

// ---------------- gemm_relu via MFMA: X = relu(Y @ WpT + bt) ----------------

__global__ __launch_bounds__(256) void gemm_relu_mfma(const u16* __restrict__ Yb,
                                                      const u16* __restrict__ Bswz,
                                                      const u16* __restrict__ btb,
                                                      u16* __restrict__ Xb, int n) {
    int tid = threadIdx.x;
    int w = tid >> 6, l = tid & 63;
    int j0 = blockIdx.x * 64 + w * 16;
    int row_a = j0 + (l & 15);
    bool rowa_ok = row_a < n;
    const short8* __restrict__ yrow = (const short8*)(Yb + (size_t)row_a * 128);
    const short8* __restrict__ bfr = (const short8*)Bswz;
    f32x4 acc[8];
    #pragma unroll
    for (int nt = 0; nt < 8; ++nt) acc[nt] = (f32x4){0.f, 0.f, 0.f, 0.f};
    #pragma unroll
    for (int kf = 0; kf < 4; ++kf) {
        short8 a = {0, 0, 0, 0, 0, 0, 0, 0};
        if (rowa_ok) a = yrow[kf * 4 + (l >> 4)];
        #pragma unroll
        for (int nt = 0; nt < 8; ++nt) {
            short8 b = bfr[(kf * 8 + nt) * 64 + l];
            acc[nt] = __builtin_amdgcn_mfma_f32_16x16x32_bf16(a, b, acc[nt], 0, 0, 0);
        }
    }
    int rbase = j0 + (l >> 4) * 4;
    int cbase = l & 15;
    #pragma unroll
    for (int nt = 0; nt < 8; ++nt) {
        int col = nt * 16 + cbase;
        #pragma unroll
        for (int i = 0; i < 4; ++i) {
            int row = rbase + i;
            if (row < n) {
                float v = acc[nt][i] + bf2f(btb[(size_t)row * 128 + col]);
                Xb[(size_t)row * 128 + col] = f2bf(v > 0.f ? v : 0.f);
            }
        }
    }
}

// ---------------- final: normalize rows + H @ Vw^T (bf16 input) ----------------

__global__ __launch_bounds__(256) void final_out(const u16* __restrict__ Xb,
                                                 const float* __restrict__ Vw,
                                                 float* __restrict__ out, int n) {
    __shared__ float Vs[40][132];
    int tid = threadIdx.x;
    int jb = blockIdx.x * 64;
    for (int i = tid; i < 40 * 128; i += 256) {
        int c = i >> 7, k = i & 127;
        Vs[c][(k >> 5) * 33 + (k & 31)] = Vw[i];
    }
    int g = tid >> 2, q = tid & 3;
    int j = jb + g;
    float xs[32];
    float ssq = 0.f;
    if (j < n) {
        const uint4* X4 = (const uint4*)(Xb + (size_t)j * 128) + q;
        #pragma unroll
        for (int v = 0; v < 4; ++v) {
            uint4 u = X4[v * 4 - (v * 4)];   // placeholder避免
            (void)u;
        }
        const uint4* X4b = (const uint4*)(Xb + (size_t)j * 128) + q * 4;
        #pragma unroll
        for (int v = 0; v < 4; ++v) {
            uint4 u = X4b[v];
            xs[v * 8 + 0] = bflo(u.x); xs[v * 8 + 1] = bfhi(u.x);
            xs[v * 8 + 2] = bflo(u.y); xs[v * 8 + 3] = bfhi(u.y);
            xs[v * 8 + 4] = bflo(u.z); xs[v * 8 + 5] = bfhi(u.z);
            xs[v * 8 + 6] = bflo(u.w); xs[v * 8 + 7] = bfhi(u.w);
        }
        #pragma unroll
        for (int m = 0; m < 32; ++m) ssq += xs[m] * xs[m];
    } else {
        #pragma unroll
        for (int m = 0; m < 32; ++m) xs[m] = 0.f;
    }
    ssq += __shfl_xor(ssq, 1, 64);
    ssq += __shfl_xor(ssq, 2, 64);
    float inv = 1.f / fmaxf(sqrtf(ssq), 1e-12f);
    #pragma unroll
    for (int m = 0; m < 32; ++m) xs[m] *= inv;
    __syncthreads();
    float pacc[10];
    #pragma unroll
    for (int cc = 0; cc < 10; ++cc) pacc[cc] = 0.f;
    #pragma unroll 1
    for (int c = 0; c < 40; ++c) {
        const float* vrow = &Vs[c][q * 33];
        float acc = 0.f;
        #pragma unroll
        for (int m = 0; m < 32; ++m) acc += xs[m] * vrow[m];
        acc += __shfl_xor(acc, 1, 64);
        acc += __shfl_xor(acc, 2, 64);
        if ((c & 3) == q) pacc[c >> 2] = acc;
    }
    if (j < n) {
        #pragma unroll
        for (int cc = 0; cc < 10; ++cc) {
            int c = cc * 4 + q;
            out[(size_t)j * 40 + c] = pacc[cc];
        }
    }
}

// ---------------- launch ----------------

extern "C" void kernel_launch(void* const* d_in, const int* in_sizes, int n_in,
                              void* d_out, int out_size, void* d_ws, size_t ws_size,
                              hipStream_t stream) {
    const float* F    = (const float*)d_in[0];   // (256, 50000)
    const float* W    = (const float*)d_in[1];   // (128, 128)
    const float* Om   = (const float*)d_in[2];   // (128, 256)
    const float* Vw   = (const float*)d_in[3];   // (40, 128)
    const float* X0   = (const float*)d_in[4];   // (128, 50000)
    const float* ew   = (const float*)d_in[5];   // (E,)
    const int*   esrc = (const int*)d_in[6];
    const int*   edst = (const int*)d_in[7];
    float* out = (float*)d_out;
    (void)in_sizes; (void)n_in; (void)out_size; (void)ws_size;

    char* ws = (char*)d_ws;
    size_t off = 0;
    auto alloc = [&](size_t bytes) -> void* {
        void* p = ws + off;
        off = (off + bytes + 255) & ~(size_t)255;
        return p;
    };
    float* buf0    = (float*)alloc((size_t)N_NODES * 4);
    float* buf1    = (float*)alloc((size_t)N_NODES * 4);
    float* ss      = (float*)alloc(64 * 4);
    int*   deg     = (int*)  alloc((size_t)(N_NODES + 1) * 4);
    int*   offs_d  = (int*)  alloc((size_t)(N_NODES + 1) * 4);
    int*   cur_d   = (int*)  alloc((size_t)N_NODES * 4);
    int*   bsum    = (int*)  alloc(512 * 4);
    int*   bbase   = (int*)  alloc(512 * 4);
    int2*  csr_d   = (int2*) alloc((size_t)N_EDGES * 8);   // by-dst: (src, w)
    u16*   Bswz    = (u16*)  alloc(128 * 128 * 2);
    float* OmT     = (float*)alloc(256 * 128 * 4);
    u16*   btb     = (u16*)  alloc((size_t)N_NODES * 128 * 2);
    float* Ut      = (float*)alloc((size_t)N_NODES * 128 * 4);
    u16*   Yb      = (u16*)  alloc((size_t)N_NODES * 128 * 2);
    u16*   Xa      = (u16*)  alloc((size_t)N_NODES * 128 * 2);
    u16*   Xb      = (u16*)  alloc((size_t)N_NODES * 128 * 2);

    hipMemsetAsync(deg, 0, (size_t)(N_NODES + 1) * 4, stream);

    const int n1 = N_NODES + 1;
    const int nb = (n1 + SBLK - 1) / SBLK;   // 196 <= 256

    // ---- CSR build (by dst only) ----
    count_deg<<<(N_EDGES + 255) / 256, 256, 0, stream>>>(edst, deg, N_EDGES);
    scan_local<<<nb, SBLK, 0, stream>>>(deg, offs_d, bsum, n1);
    scan_bsum<<<1, SBLK, 0, stream>>>(bsum, bbase, nb);
    scan_add<<<nb, SBLK, 0, stream>>>(offs_d, cur_d, bbase, n1);
    fill_csr<<<(N_EDGES + 255) / 256, 256, 0, stream>>>(
        esrc, edst, ew, cur_d, csr_d, N_EDGES);

    // ---- power iteration on A^T (rho identical): 1 gather-matvec per step ----
    fill_pow<<<(N_NODES + 255) / 256, 256, 0, stream>>>(
        buf0, ss, N_NODES, 1.f / sqrtf((float)N_NODES));
    float* bufs[2] = {buf0, buf1};
    for (int it = 0; it <= PWR_ITERS; ++it) {
        matvec_norm<<<(4 * N_NODES + 255) / 256, 256, 0, stream>>>(
            offs_d, csr_d, bufs[it & 1], ss + it,
            bufs[(it + 1) & 1], ss + it + 1, N_NODES);
    }

    // ---- project W (rho^2 = ss[PWR_ITERS+1]) -> Bswz fragments ----
    project_w<<<128, 128, 0, stream>>>(W, ss + PWR_ITERS + 1, Bswz);

    // ---- b = (Omega_1 @ U) @ A  -> bf16 ----
    transpose_om<<<(128 * 256 + 255) / 256, 256, 0, stream>>>(Om, OmT);
    gemm_u<<<(N_NODES + 63) / 64, 256, 0, stream>>>(F, OmT, Ut, N_NODES);
    spmm_f32<<<(N_NODES + 3) / 4, 256, 0, stream>>>(offs_d, csr_d, Ut, btb, N_NODES);

    // ---- fixed point (bf16 X/Y, MFMA gemm) ----
    transpose_x0_bf16<<<dim3((N_NODES + 31) / 32, 4), dim3(32, 8), 0, stream>>>(X0, Xa, N_NODES);
    u16* xb2[2] = {Xa, Xb};
    for (int it = 0; it < FP_ITERS; ++it) {
        spmm_bf16<<<(N_NODES + 3) / 4, 256, 0, stream>>>(
            offs_d, csr_d, xb2[it & 1], Yb, N_NODES);
        gemm_relu_mfma<<<(N_NODES + 63) / 64, 256, 0, stream>>>(
            Yb, Bswz, btb, xb2[(it + 1) & 1], N_NODES);
    }

    // ---- output ----
    final_out<<<(N_NODES + 63) / 64, 256, 0, stream>>>(xb2[FP_ITERS & 1], Vw, out, N_NODES);
}

// Round 9
// 2319.062 us; speedup vs baseline: 1.8776x; 1.2369x over previous
//
#include <hip/hip_runtime.h>
#include <math.h>

#define N_NODES 50000
#define N_EDGES 800000
#define M_HID   128
#define P_FEAT  256
#define C_OUT   40
#define PWR_ITERS 32
#define FP_ITERS  30
#define KAPPA 0.9f
#define SBLK 256

typedef unsigned short u16;
typedef unsigned int   u32;
typedef __attribute__((ext_vector_type(8))) short short8;
typedef __attribute__((ext_vector_type(4))) float f32x4;

// bf16 helpers (RNE)
__device__ inline u16 f2bf(float f) {
    union { float f; u32 u; } c; c.f = f;
    u32 u = c.u + 0x7fffu + ((c.u >> 16) & 1u);
    return (u16)(u >> 16);
}
__device__ inline float bf2f(u16 h) { union { u32 u; float f; } c; c.u = (u32)h << 16; return c.f; }
__device__ inline float bflo(u32 u) { union { u32 u; float f; } c; c.u = u << 16; return c.f; }
__device__ inline float bfhi(u32 u) { union { u32 u; float f; } c; c.u = u & 0xffff0000u; return c.f; }

// ---------------- init ----------------

__global__ void fill_pow(float* buf0, float* ss, int n, float val) {
    int i = blockIdx.x * blockDim.x + threadIdx.x;
    if (i < n) buf0[i] = val;
    if (blockIdx.x == 0 && threadIdx.x < 64) ss[threadIdx.x] = (threadIdx.x == 0) ? 1.f : 0.f;
}

// ---------------- power iteration on A^T (same spectral radius): 4-lane/node ----

__global__ __launch_bounds__(256) void matvec_norm(const int* __restrict__ offs,
                                                   const int2* __restrict__ csr,
                                                   const float* __restrict__ vin,
                                                   const float* __restrict__ n2in,
                                                   float* __restrict__ vout,
                                                   float* n2out, int n) {
    int t = blockIdx.x * blockDim.x + threadIdx.x;
    int g = t >> 2, q = t & 3;
    float inv = 1.f / (sqrtf(*n2in) + 1e-12f);
    float a = 0.f;
    if (g < n) {
        int lo = offs[g], hi = offs[g + 1];
        for (int e = lo + q; e < hi; e += 4) {
            int2 c = csr[e];
            a += __int_as_float(c.y) * vin[c.x];
        }
    }
    a += __shfl_xor(a, 1, 64);
    a += __shfl_xor(a, 2, 64);
    a *= inv;
    if (g < n && q == 0) vout[g] = a;
    float s = (q == 0 && g < n) ? a * a : 0.f;
    for (int o = 32; o > 0; o >>= 1) s += __shfl_down(s, o, 64);
    __shared__ float ls[4];
    int lane = threadIdx.x & 63, wid = threadIdx.x >> 6;
    if (lane == 0) ls[wid] = s;
    __syncthreads();
    if (threadIdx.x == 0) atomicAdd(n2out, ls[0] + ls[1] + ls[2] + ls[3]);
}

// ---------------- L1-ball row projection of W -> MFMA B-fragment layout ----------------

__global__ __launch_bounds__(128) void project_w(const float* __restrict__ W,
                                                 const float* __restrict__ rho2,
                                                 u16* __restrict__ Bswz) {
    __shared__ float sa[128];
    __shared__ float ssort[128];
    __shared__ float sc[128];
    __shared__ int cnt2[2];
    int r = blockIdx.x, t = threadIdx.x;
    float radius = KAPPA / sqrtf(*rho2);
    float w0 = W[r * 128 + t];
    float a = fabsf(w0);
    sa[t] = a;
    __syncthreads();
    int rank = 0;
    #pragma unroll 8
    for (int j = 0; j < 128; ++j) {
        float aj = sa[j];
        rank += (aj > a) || (aj == a && j < t);
    }
    ssort[rank] = a;
    __syncthreads();
    sc[t] = ssort[t];
    __syncthreads();
    for (int off = 1; off < 128; off <<= 1) {
        float add = (t >= off) ? sc[t - off] : 0.f;
        __syncthreads();
        sc[t] += add;
        __syncthreads();
    }
    bool flag = ssort[t] * (float)(t + 1) > sc[t] - radius;
    unsigned long long b = __ballot(flag);
    if ((t & 63) == 0) cnt2[t >> 6] = __popcll(b);
    __syncthreads();
    int rho = cnt2[0] + cnt2[1];
    float total = sc[127];
    bool needs = total > radius;
    float theta = (sc[rho - 1] - radius) / (float)rho;
    float o;
    if (needs) {
        float am = a - theta;
        o = (am > 0.f) ? ((w0 > 0.f) ? am : -am) : 0.f;
    } else o = w0;
    // scatter into B-fragment layout
    int kf = t >> 5, quad = (t >> 3) & 3, jj = t & 7;
    int nt = r >> 4, li = r & 15;
    int l = quad * 16 + li;
    Bswz[((size_t)(kf * 8 + nt) * 64 + l) * 8 + jj] = f2bf(o);
}

// ---------------- CSR build (by dst only), int2-packed ----------------

__global__ void count_deg(const int* __restrict__ dst, int* deg, int E) {
    int e = blockIdx.x * blockDim.x + threadIdx.x;
    if (e < E) atomicAdd(&deg[dst[e]], 1);
}

__global__ __launch_bounds__(SBLK) void scan_local(const int* __restrict__ deg,
                                                   int* __restrict__ offsets,
                                                   int* __restrict__ bsum, int n1) {
    __shared__ int s[SBLK];
    int i = blockIdx.x * SBLK + threadIdx.x;
    int v = (i < n1 - 1) ? deg[i] : 0;
    s[threadIdx.x] = v;
    __syncthreads();
    for (int o = 1; o < SBLK; o <<= 1) {
        int add = (threadIdx.x >= o) ? s[threadIdx.x - o] : 0;
        __syncthreads();
        s[threadIdx.x] += add;
        __syncthreads();
    }
    if (i < n1) offsets[i] = s[threadIdx.x] - v;   // exclusive
    if (threadIdx.x == SBLK - 1) bsum[blockIdx.x] = s[SBLK - 1];
}

__global__ __launch_bounds__(SBLK) void scan_bsum(const int* __restrict__ bsum,
                                                  int* __restrict__ bbase, int nb) {
    __shared__ int s[SBLK];
    int v = (threadIdx.x < nb) ? bsum[threadIdx.x] : 0;
    s[threadIdx.x] = v;
    __syncthreads();
    for (int o = 1; o < SBLK; o <<= 1) {
        int add = (threadIdx.x >= o) ? s[threadIdx.x - o] : 0;
        __syncthreads();
        s[threadIdx.x] += add;
        __syncthreads();
    }
    if (threadIdx.x < nb) bbase[threadIdx.x] = s[threadIdx.x] - v;
}

__global__ __launch_bounds__(SBLK) void scan_add(int* __restrict__ offsets,
                                                 int* __restrict__ cursor,
                                                 const int* __restrict__ bbase, int n1) {
    int i = blockIdx.x * SBLK + threadIdx.x;
    if (i < n1) {
        int o = offsets[i] + bbase[blockIdx.x];
        offsets[i] = o;
        if (i < n1 - 1) cursor[i] = o;
    }
}

__global__ void fill_csr(const int* __restrict__ src, const int* __restrict__ dst,
                         const float* __restrict__ w,
                         int* cur_d, int2* csr_d, int E) {
    int e = blockIdx.x * blockDim.x + threadIdx.x;
    if (e < E) {
        int d = dst[e];
        int pd = atomicAdd(&cur_d[d], 1);
        csr_d[pd] = make_int2(src[e], __float_as_int(w[e]));
    }
}

// ---------------- small transposes ----------------

__global__ void transpose_om(const float* __restrict__ Om, float* OmT) {
    int idx = blockIdx.x * blockDim.x + threadIdx.x;
    if (idx < 128 * 256) {
        int t = idx / 256, k = idx % 256;
        OmT[k * 128 + t] = Om[idx];
    }
}

__global__ void transpose_x0_bf16(const float* __restrict__ X0, u16* Xb, int n) {
    __shared__ float tile[32][33];
    int jb = blockIdx.x * 32, tb = blockIdx.y * 32;
    int tx = threadIdx.x, ty = threadIdx.y;
    for (int r = 0; r < 32; r += 8) {
        int t = tb + ty + r, j = jb + tx;
        tile[ty + r][tx] = (j < n) ? X0[(size_t)t * n + j] : 0.f;
    }
    __syncthreads();
    for (int r = 0; r < 32; r += 8) {
        int j = jb + ty + r, t = tb + tx;
        if (j < n) Xb[(size_t)j * 128 + t] = f2bf(tile[tx][ty + r]);
    }
}

// ---------------- one-shot dense GEMM: Ut = F^T @ OmT (f32, 64-row tiles) ----------

__global__ __launch_bounds__(256) void gemm_u(const float* __restrict__ F,
                                              const float* __restrict__ OmT,
                                              float* __restrict__ C, int n) {
    __shared__ float Fs[16][65];
    __shared__ float Bs[16][129];
    int j0 = blockIdx.x * 64;
    int tid = threadIdx.x;
    int tj = tid >> 4, tg = tid & 15;
    float acc[4][8] = {};
    for (int k0 = 0; k0 < 256; k0 += 16) {
        #pragma unroll
        for (int r = 0; r < 4; ++r) {
            int idx = r * 256 + tid;
            int kk = idx >> 6, jj = idx & 63;
            int j = j0 + jj;
            Fs[kk][jj] = (j < n) ? F[(size_t)(k0 + kk) * n + j] : 0.f;
        }
        #pragma unroll
        for (int r = 0; r < 8; ++r) {
            int idx = r * 256 + tid;
            int kk = idx >> 7, tt = idx & 127;
            Bs[kk][tt] = OmT[(k0 + kk) * 128 + tt];
        }
        __syncthreads();
        #pragma unroll
        for (int kk = 0; kk < 16; ++kk) {
            float a[4], b[8];
            #pragma unroll
            for (int u = 0; u < 4; ++u) a[u] = Fs[kk][tj + 16 * u];
            #pragma unroll
            for (int u = 0; u < 8; ++u) b[u] = Bs[kk][tg + 16 * u];
            #pragma unroll
            for (int x = 0; x < 4; ++x)
                #pragma unroll
                for (int y = 0; y < 8; ++y)
                    acc[x][y] += a[x] * b[y];
        }
        __syncthreads();
    }
    #pragma unroll
    for (int x = 0; x < 4; ++x) {
        int j = j0 + tj + 16 * x;
        if (j < n)
            #pragma unroll
            for (int y = 0; y < 8; ++y)
                C[(size_t)j * 128 + tg + 16 * y] = acc[x][y];
    }
}

// ---------------- spmm f32 -> bf16 bias (row-major): bt = (U @ A) ----------------

__global__ __launch_bounds__(256) void spmm_f32(const int* __restrict__ offsets,
                                                const int2* __restrict__ csr,
                                                const float* __restrict__ Xin,
                                                u16* __restrict__ Yout, int n) {
    int j = blockIdx.x * 4 + (threadIdx.x >> 6);
    if (j >= n) return;
    int lane = threadIdx.x & 63;
    int lo = offsets[j], hi = offsets[j + 1];
    const float2* __restrict__ X2 = (const float2*)Xin;
    float2 acc = {0.f, 0.f};
    int e = lo;
    for (; e + 8 <= hi; e += 8) {
        int2 c[8];
        #pragma unroll
        for (int u = 0; u < 8; ++u) c[u] = csr[e + u];
        float2 x[8];
        #pragma unroll
        for (int u = 0; u < 8; ++u) x[u] = X2[(size_t)c[u].x * 64 + lane];
        #pragma unroll
        for (int u = 0; u < 8; ++u) {
            float w = __int_as_float(c[u].y);
            acc.x += w * x[u].x;
            acc.y += w * x[u].y;
        }
    }
    for (; e < hi; ++e) {
        int2 c = csr[e];
        float w = __int_as_float(c.y);
        float2 x = X2[(size_t)c.x * 64 + lane];
        acc.x += w * x.x;
        acc.y += w * x.y;
    }
    ((u32*)Yout)[(size_t)j * 64 + lane] = (u32)f2bf(acc.x) | ((u32)f2bf(acc.y) << 16);
}

// ---------------- reorder bias into MFMA C-fragment layout ----------------
// btf[((idx16*8 + nt)*64 + lane)] = uint2 of bias for rows r0..r0+3, col c
//   where r0 = idx16*16 + (lane>>4)*4, c = nt*16 + (lane&15).

__global__ __launch_bounds__(256) void reorder_bt(const u16* __restrict__ btr,
                                                  uint2* __restrict__ btf) {
    int t = blockIdx.y * 256 + threadIdx.x;   // 0..511
    int idx16 = blockIdx.x;
    int nt = t >> 6, lane = t & 63;
    int r0 = idx16 * 16 + (lane >> 4) * 4;
    int c = nt * 16 + (lane & 15);
    u16 b0 = btr[(size_t)(r0 + 0) * 128 + c];
    u16 b1 = btr[(size_t)(r0 + 1) * 128 + c];
    u16 b2 = btr[(size_t)(r0 + 2) * 128 + c];
    u16 b3 = btr[(size_t)(r0 + 3) * 128 + c];
    uint2 o;
    o.x = (u32)b0 | ((u32)b1 << 16);
    o.y = (u32)b2 | ((u32)b3 << 16);
    btf[(size_t)(idx16 * 8 + nt) * 64 + lane] = o;
}

// ---------------- spmm bf16 (FP loop): Y = X @ A ----------------
// Quarter-wave (16 lanes) per dst row; lane li owns cols li*8..li*8+7 (uint4).
// No cross-lane reduction needed.

__global__ __launch_bounds__(256) void spmm_bf16(const int* __restrict__ offsets,
                                                 const int2* __restrict__ csr,
                                                 const u16* __restrict__ Xin,
                                                 u16* __restrict__ Yout, int n) {
    int tid = threadIdx.x;
    int wid = tid >> 6, lane = tid & 63;
    int q = lane >> 4, li = lane & 15;
    int j = blockIdx.x * 16 + wid * 4 + q;
    if (j >= n) return;
    int lo = offsets[j], hi = offsets[j + 1];
    const uint4* __restrict__ X4 = (const uint4*)Xin;   // 16 x 16B per row
    float a[8] = {};
    int e = lo;
    for (; e + 8 <= hi; e += 8) {
        int2 c[8];
        #pragma unroll
        for (int u = 0; u < 8; ++u) c[u] = csr[e + u];
        uint4 x[8];
        #pragma unroll
        for (int u = 0; u < 8; ++u) x[u] = X4[(size_t)c[u].x * 16 + li];
        #pragma unroll
        for (int u = 0; u < 8; ++u) {
            float w = __int_as_float(c[u].y);
            a[0] += w * bflo(x[u].x); a[1] += w * bfhi(x[u].x);
            a[2] += w * bflo(x[u].y); a[3] += w * bfhi(x[u].y);
            a[4] += w * bflo(x[u].z); a[5] += w * bfhi(x[u].z);
            a[6] += w * bflo(x[u].w); a[7] += w * bfhi(x[u].w);
        }
    }
    for (; e < hi; ++e) {
        int2 c = csr[e];
        float w = __int_as_float(c.y);
        uint4 x = X4[(size_t)c.x * 16 + li];
        a[0] += w * bflo(x.x); a[1] += w * bfhi(x.x);
        a[2] += w * bflo(x.y); a[3] += w * bfhi(x.y);
        a[4] += w * bflo(x.z); a[5] += w * bfhi(x.z);
        a[6] += w * bflo(x.w); a[7] += w * bfhi(x.w);
    }
    uint4 o;
    o.x = (u32)f2bf(a[0]) | ((u32)f2bf(a[1]) << 16);
    o.y = (u32)f2bf(a[2]) | ((u32)f2bf(a[3]) << 16);
    o.z = (u32)f2bf(a[4]) | ((u32)f2bf(a[5]) << 16);
    o.w = (u32)f2bf(a[6]) | ((u32)f2bf(a[7]) << 16);
    ((uint4*)Yout)[(size_t)j * 16 + li] = o;
}

// ---------------- gemm_relu via MFMA: X = relu(Y @ WpT + b) ----------------
// 256 thr = 4 waves; block = 64 rows; bias read coalesced from fragment layout.

__global__ __launch_bounds__(256) void gemm_relu_mfma(const u16* __restrict__ Yb,
                                                      const u16* __restrict__ Bswz,
                                                      const uint2* __restrict__ btf,
                                                      u16* __restrict__ Xb, int n) {
    int tid = threadIdx.x;
    int w = tid >> 6, l = tid & 63;
    int j0 = blockIdx.x * 64 + w * 16;
    int idx16 = blockIdx.x * 4 + w;
    int row_a = j0 + (l & 15);
    bool rowa_ok = row_a < n;
    const short8* __restrict__ yrow = (const short8*)(Yb + (size_t)row_a * 128);
    const short8* __restrict__ bfr = (const short8*)Bswz;
    f32x4 acc[8];
    #pragma unroll
    for (int nt = 0; nt < 8; ++nt) acc[nt] = (f32x4){0.f, 0.f, 0.f, 0.f};
    #pragma unroll
    for (int kf = 0; kf < 4; ++kf) {
        short8 a = {0, 0, 0, 0, 0, 0, 0, 0};
        if (rowa_ok) a = yrow[kf * 4 + (l >> 4)];
        #pragma unroll
        for (int nt = 0; nt < 8; ++nt) {
            short8 b = bfr[(kf * 8 + nt) * 64 + l];
            acc[nt] = __builtin_amdgcn_mfma_f32_16x16x32_bf16(a, b, acc[nt], 0, 0, 0);
        }
    }
    int rbase = j0 + (l >> 4) * 4;
    int cbase = l & 15;
    #pragma unroll
    for (int nt = 0; nt < 8; ++nt) {
        uint2 bb = btf[(size_t)(idx16 * 8 + nt) * 64 + l];
        float bi0 = bflo(bb.x), bi1 = bfhi(bb.x), bi2 = bflo(bb.y), bi3 = bfhi(bb.y);
        int col = nt * 16 + cbase;
        float v0 = acc[nt][0] + bi0;
        float v1 = acc[nt][1] + bi1;
        float v2 = acc[nt][2] + bi2;
        float v3 = acc[nt][3] + bi3;
        if (rbase + 0 < n) Xb[(size_t)(rbase + 0) * 128 + col] = f2bf(v0 > 0.f ? v0 : 0.f);
        if (rbase + 1 < n) Xb[(size_t)(rbase + 1) * 128 + col] = f2bf(v1 > 0.f ? v1 : 0.f);
        if (rbase + 2 < n) Xb[(size_t)(rbase + 2) * 128 + col] = f2bf(v2 > 0.f ? v2 : 0.f);
        if (rbase + 3 < n) Xb[(size_t)(rbase + 3) * 128 + col] = f2bf(v3 > 0.f ? v3 : 0.f);
    }
}

// ---------------- final: normalize rows + H @ Vw^T (bf16 input) ----------------

__global__ __launch_bounds__(256) void final_out(const u16* __restrict__ Xb,
                                                 const float* __restrict__ Vw,
                                                 float* __restrict__ out, int n) {
    __shared__ float Vs[40][132];
    int tid = threadIdx.x;
    int jb = blockIdx.x * 64;
    for (int i = tid; i < 40 * 128; i += 256) {
        int c = i >> 7, k = i & 127;
        Vs[c][(k >> 5) * 33 + (k & 31)] = Vw[i];
    }
    int g = tid >> 2, q = tid & 3;
    int j = jb + g;
    float xs[32];
    float ssq = 0.f;
    if (j < n) {
        const uint4* X4 = (const uint4*)(Xb + (size_t)j * 128) + q * 4;
        #pragma unroll
        for (int v = 0; v < 4; ++v) {
            uint4 u = X4[v];
            xs[v * 8 + 0] = bflo(u.x); xs[v * 8 + 1] = bfhi(u.x);
            xs[v * 8 + 2] = bflo(u.y); xs[v * 8 + 3] = bfhi(u.y);
            xs[v * 8 + 4] = bflo(u.z); xs[v * 8 + 5] = bfhi(u.z);
            xs[v * 8 + 6] = bflo(u.w); xs[v * 8 + 7] = bfhi(u.w);
        }
        #pragma unroll
        for (int m = 0; m < 32; ++m) ssq += xs[m] * xs[m];
    } else {
        #pragma unroll
        for (int m = 0; m < 32; ++m) xs[m] = 0.f;
    }
    ssq += __shfl_xor(ssq, 1, 64);
    ssq += __shfl_xor(ssq, 2, 64);
    float inv = 1.f / fmaxf(sqrtf(ssq), 1e-12f);
    #pragma unroll
    for (int m = 0; m < 32; ++m) xs[m] *= inv;
    __syncthreads();
    float pacc[10];
    #pragma unroll
    for (int cc = 0; cc < 10; ++cc) pacc[cc] = 0.f;
    #pragma unroll 1
    for (int c = 0; c < 40; ++c) {
        const float* vrow = &Vs[c][q * 33];
        float acc = 0.f;
        #pragma unroll
        for (int m = 0; m < 32; ++m) acc += xs[m] * vrow[m];
        acc += __shfl_xor(acc, 1, 64);
        acc += __shfl_xor(acc, 2, 64);
        if ((c & 3) == q) pacc[c >> 2] = acc;
    }
    if (j < n) {
        #pragma unroll
        for (int cc = 0; cc < 10; ++cc) {
            int c = cc * 4 + q;
            out[(size_t)j * 40 + c] = pacc[cc];
        }
    }
}

// ---------------- launch ----------------

extern "C" void kernel_launch(void* const* d_in, const int* in_sizes, int n_in,
                              void* d_out, int out_size, void* d_ws, size_t ws_size,
                              hipStream_t stream) {
    const float* F    = (const float*)d_in[0];   // (256, 50000)
    const float* W    = (const float*)d_in[1];   // (128, 128)
    const float* Om   = (const float*)d_in[2];   // (128, 256)
    const float* Vw   = (const float*)d_in[3];   // (40, 128)
    const float* X0   = (const float*)d_in[4];   // (128, 50000)
    const float* ew   = (const float*)d_in[5];   // (E,)
    const int*   esrc = (const int*)d_in[6];
    const int*   edst = (const int*)d_in[7];
    float* out = (float*)d_out;
    (void)in_sizes; (void)n_in; (void)out_size; (void)ws_size;

    char* ws = (char*)d_ws;
    size_t off = 0;
    auto alloc = [&](size_t bytes) -> void* {
        void* p = ws + off;
        off = (off + bytes + 255) & ~(size_t)255;
        return p;
    };
    float* buf0    = (float*)alloc((size_t)N_NODES * 4);
    float* buf1    = (float*)alloc((size_t)N_NODES * 4);
    float* ss      = (float*)alloc(64 * 4);
    int*   deg     = (int*)  alloc((size_t)(N_NODES + 1) * 4);
    int*   offs_d  = (int*)  alloc((size_t)(N_NODES + 1) * 4);
    int*   cur_d   = (int*)  alloc((size_t)N_NODES * 4);
    int*   bsum    = (int*)  alloc(512 * 4);
    int*   bbase   = (int*)  alloc(512 * 4);
    int2*  csr_d   = (int2*) alloc((size_t)N_EDGES * 8);   // by-dst: (src, w)
    u16*   Bswz    = (u16*)  alloc(128 * 128 * 2);
    float* OmT     = (float*)alloc(256 * 128 * 4);
    u16*   btr     = (u16*)  alloc((size_t)N_NODES * 128 * 2);    // bias row-major
    uint2* btf     = (uint2*)alloc((size_t)3128 * 512 * 8);       // bias C-frag (padded)
    float* Ut      = (float*)alloc((size_t)N_NODES * 128 * 4);
    u16*   Yb      = (u16*)  alloc((size_t)N_NODES * 128 * 2);
    u16*   Xa      = (u16*)  alloc((size_t)N_NODES * 128 * 2);
    u16*   Xb      = (u16*)  alloc((size_t)N_NODES * 128 * 2);

    hipMemsetAsync(deg, 0, (size_t)(N_NODES + 1) * 4, stream);

    const int n1 = N_NODES + 1;
    const int nb = (n1 + SBLK - 1) / SBLK;   // 196 <= 256

    // ---- CSR build (by dst only) ----
    count_deg<<<(N_EDGES + 255) / 256, 256, 0, stream>>>(edst, deg, N_EDGES);
    scan_local<<<nb, SBLK, 0, stream>>>(deg, offs_d, bsum, n1);
    scan_bsum<<<1, SBLK, 0, stream>>>(bsum, bbase, nb);
    scan_add<<<nb, SBLK, 0, stream>>>(offs_d, cur_d, bbase, n1);
    fill_csr<<<(N_EDGES + 255) / 256, 256, 0, stream>>>(
        esrc, edst, ew, cur_d, csr_d, N_EDGES);

    // ---- power iteration on A^T (rho identical, converged by 32 iters) ----
    fill_pow<<<(N_NODES + 255) / 256, 256, 0, stream>>>(
        buf0, ss, N_NODES, 1.f / sqrtf((float)N_NODES));
    float* bufs[2] = {buf0, buf1};
    for (int it = 0; it <= PWR_ITERS; ++it) {
        matvec_norm<<<(4 * N_NODES + 255) / 256, 256, 0, stream>>>(
            offs_d, csr_d, bufs[it & 1], ss + it,
            bufs[(it + 1) & 1], ss + it + 1, N_NODES);
    }

    // ---- project W (rho^2 = ss[PWR_ITERS+1]) -> Bswz fragments ----
    project_w<<<128, 128, 0, stream>>>(W, ss + PWR_ITERS + 1, Bswz);

    // ---- b = (Omega_1 @ U) @ A  -> bf16 row-major -> C-frag layout ----
    transpose_om<<<(128 * 256 + 255) / 256, 256, 0, stream>>>(Om, OmT);
    gemm_u<<<(N_NODES + 63) / 64, 256, 0, stream>>>(F, OmT, Ut, N_NODES);
    spmm_f32<<<(N_NODES + 3) / 4, 256, 0, stream>>>(offs_d, csr_d, Ut, btr, N_NODES);
    reorder_bt<<<dim3(N_NODES / 16, 2), 256, 0, stream>>>(btr, btf);

    // ---- fixed point (bf16 X/Y, MFMA gemm) ----
    transpose_x0_bf16<<<dim3((N_NODES + 31) / 32, 4), dim3(32, 8), 0, stream>>>(X0, Xa, N_NODES);
    u16* xb2[2] = {Xa, Xb};
    for (int it = 0; it < FP_ITERS; ++it) {
        spmm_bf16<<<(N_NODES + 15) / 16, 256, 0, stream>>>(
            offs_d, csr_d, xb2[it & 1], Yb, N_NODES);
        gemm_relu_mfma<<<(N_NODES + 63) / 64, 256, 0, stream>>>(
            Yb, Bswz, btf, xb2[(it + 1) & 1], N_NODES);
    }

    // ---- output ----
    final_out<<<(N_NODES + 63) / 64, 256, 0, stream>>>(xb2[FP_ITERS & 1], Vw, out, N_NODES);
}

// Round 10
// 2145.477 us; speedup vs baseline: 2.0295x; 1.0809x over previous
//
#include <hip/hip_runtime.h>
#include <math.h>

#define N_NODES 50000
#define N_EDGES 800000
#define M_HID   128
#define P_FEAT  256
#define C_OUT   40
#define PWR_ITERS 16
#define FP_ITERS  30
#define KAPPA 0.9f
#define SBLK 256

typedef unsigned short u16;
typedef unsigned int   u32;
typedef __attribute__((ext_vector_type(8))) short short8;
typedef __attribute__((ext_vector_type(4))) float f32x4;

// bf16 helpers (RNE)
__device__ inline u16 f2bf(float f) {
    union { float f; u32 u; } c; c.f = f;
    u32 u = c.u + 0x7fffu + ((c.u >> 16) & 1u);
    return (u16)(u >> 16);
}
__device__ inline u32 pack2bf(float lo, float hi) {
    return (u32)f2bf(lo) | ((u32)f2bf(hi) << 16);
}
__device__ inline float bflo(u32 u) { union { u32 u; float f; } c; c.u = u << 16; return c.f; }
__device__ inline float bfhi(u32 u) { union { u32 u; float f; } c; c.u = u & 0xffff0000u; return c.f; }

// ---------------- init ----------------

__global__ void fill_pow(float* buf0, float* ss, int n, float val) {
    int i = blockIdx.x * blockDim.x + threadIdx.x;
    if (i < n) buf0[i] = val;
    if (blockIdx.x == 0 && threadIdx.x < 64) ss[threadIdx.x] = (threadIdx.x == 0) ? 1.f : 0.f;
}

// ---------------- power iteration on A^T (same rho): 8 lanes/node ----------------

__global__ __launch_bounds__(256) void matvec_norm(const int* __restrict__ offs,
                                                   const int2* __restrict__ csr,
                                                   const float* __restrict__ vin,
                                                   const float* __restrict__ n2in,
                                                   float* __restrict__ vout,
                                                   float* n2out, int n) {
    int t = blockIdx.x * blockDim.x + threadIdx.x;
    int g = t >> 3, q = t & 7;
    float inv = 1.f / (sqrtf(*n2in) + 1e-12f);
    float a = 0.f;
    if (g < n) {
        int lo = offs[g], hi = offs[g + 1];
        for (int e = lo + q; e < hi; e += 8) {
            int2 c = csr[e];
            a += __int_as_float(c.y) * vin[c.x];
        }
    }
    a += __shfl_xor(a, 1, 64);
    a += __shfl_xor(a, 2, 64);
    a += __shfl_xor(a, 4, 64);
    a *= inv;
    if (g < n && q == 0) vout[g] = a;
    float s = (q == 0 && g < n) ? a * a : 0.f;
    for (int o = 32; o > 0; o >>= 1) s += __shfl_down(s, o, 64);
    __shared__ float ls[4];
    int lane = threadIdx.x & 63, wid = threadIdx.x >> 6;
    if (lane == 0) ls[wid] = s;
    __syncthreads();
    if (threadIdx.x == 0) atomicAdd(n2out, ls[0] + ls[1] + ls[2] + ls[3]);
}

// ---------------- L1-ball row projection of W -> MFMA B-fragment layout ----------------

__global__ __launch_bounds__(128) void project_w(const float* __restrict__ W,
                                                 const float* __restrict__ rho2,
                                                 u16* __restrict__ Bswz) {
    __shared__ float sa[128];
    __shared__ float ssort[128];
    __shared__ float sc[128];
    __shared__ int cnt2[2];
    int r = blockIdx.x, t = threadIdx.x;
    float radius = KAPPA / sqrtf(*rho2);
    float w0 = W[r * 128 + t];
    float a = fabsf(w0);
    sa[t] = a;
    __syncthreads();
    int rank = 0;
    #pragma unroll 8
    for (int j = 0; j < 128; ++j) {
        float aj = sa[j];
        rank += (aj > a) || (aj == a && j < t);
    }
    ssort[rank] = a;
    __syncthreads();
    sc[t] = ssort[t];
    __syncthreads();
    for (int off = 1; off < 128; off <<= 1) {
        float add = (t >= off) ? sc[t - off] : 0.f;
        __syncthreads();
        sc[t] += add;
        __syncthreads();
    }
    bool flag = ssort[t] * (float)(t + 1) > sc[t] - radius;
    unsigned long long b = __ballot(flag);
    if ((t & 63) == 0) cnt2[t >> 6] = __popcll(b);
    __syncthreads();
    int rho = cnt2[0] + cnt2[1];
    float total = sc[127];
    bool needs = total > radius;
    float theta = (sc[rho - 1] - radius) / (float)rho;
    float o;
    if (needs) {
        float am = a - theta;
        o = (am > 0.f) ? ((w0 > 0.f) ? am : -am) : 0.f;
    } else o = w0;
    // scatter into B-fragment layout (K=128: kf 0..3)
    int kf = t >> 5, quad = (t >> 3) & 3, jj = t & 7;
    int nt = r >> 4, li = r & 15;
    int l = quad * 16 + li;
    Bswz[((size_t)(kf * 8 + nt) * 64 + l) * 8 + jj] = f2bf(o);
}

// ---------------- Omega_1 -> MFMA B-fragment layout (K=256: kf 0..7) ----------------
// B[k][c=t] = Om[t*256 + k]; frag elem (kf,nt,lane l,reg jj) = B[kf*32+(l>>4)*8+jj][nt*16+(l&15)]

__global__ __launch_bounds__(256) void reorder_om(const float* __restrict__ Om,
                                                  u16* __restrict__ Ofrg) {
    int idx = blockIdx.x * 256 + threadIdx.x;   // 128*256
    int r = idx >> 8, k = idx & 255;
    int nt = r >> 4, li = r & 15;
    int kf = k >> 5, sub = (k >> 3) & 3, jj = k & 7;
    int l = sub * 16 + li;
    Ofrg[((size_t)(kf * 8 + nt) * 64 + l) * 8 + jj] = f2bf(Om[idx]);
}

// ---------------- CSR build (by dst only), int2-packed ----------------

__global__ void count_deg(const int* __restrict__ dst, int* deg, int E) {
    int e = blockIdx.x * blockDim.x + threadIdx.x;
    if (e < E) atomicAdd(&deg[dst[e]], 1);
}

__global__ __launch_bounds__(SBLK) void scan_local(const int* __restrict__ deg,
                                                   int* __restrict__ offsets,
                                                   int* __restrict__ bsum, int n1) {
    __shared__ int s[SBLK];
    int i = blockIdx.x * SBLK + threadIdx.x;
    int v = (i < n1 - 1) ? deg[i] : 0;
    s[threadIdx.x] = v;
    __syncthreads();
    for (int o = 1; o < SBLK; o <<= 1) {
        int add = (threadIdx.x >= o) ? s[threadIdx.x - o] : 0;
        __syncthreads();
        s[threadIdx.x] += add;
        __syncthreads();
    }
    if (i < n1) offsets[i] = s[threadIdx.x] - v;   // exclusive
    if (threadIdx.x == SBLK - 1) bsum[blockIdx.x] = s[SBLK - 1];
}

__global__ __launch_bounds__(SBLK) void scan_bsum(const int* __restrict__ bsum,
                                                  int* __restrict__ bbase, int nb) {
    __shared__ int s[SBLK];
    int v = (threadIdx.x < nb) ? bsum[threadIdx.x] : 0;
    s[threadIdx.x] = v;
    __syncthreads();
    for (int o = 1; o < SBLK; o <<= 1) {
        int add = (threadIdx.x >= o) ? s[threadIdx.x - o] : 0;
        __syncthreads();
        s[threadIdx.x] += add;
        __syncthreads();
    }
    if (threadIdx.x < nb) bbase[threadIdx.x] = s[threadIdx.x] - v;
}

__global__ __launch_bounds__(SBLK) void scan_add(int* __restrict__ offsets,
                                                 int* __restrict__ cursor,
                                                 const int* __restrict__ bbase, int n1) {
    int i = blockIdx.x * SBLK + threadIdx.x;
    if (i < n1) {
        int o = offsets[i] + bbase[blockIdx.x];
        offsets[i] = o;
        if (i < n1 - 1) cursor[i] = o;
    }
}

__global__ void fill_csr(const int* __restrict__ src, const int* __restrict__ dst,
                         const float* __restrict__ w,
                         int* cur_d, int2* csr_d, int E) {
    int e = blockIdx.x * blockDim.x + threadIdx.x;
    if (e < E) {
        int d = dst[e];
        int pd = atomicAdd(&cur_d[d], 1);
        csr_d[pd] = make_int2(src[e], __float_as_int(w[e]));
    }
}

// ---------------- transpose X0 -> bf16 ----------------

__global__ void transpose_x0_bf16(const float* __restrict__ X0, u16* Xb, int n) {
    __shared__ float tile[32][33];
    int jb = blockIdx.x * 32, tb = blockIdx.y * 32;
    int tx = threadIdx.x, ty = threadIdx.y;
    for (int r = 0; r < 32; r += 8) {
        int t = tb + ty + r, j = jb + tx;
        tile[ty + r][tx] = (j < n) ? X0[(size_t)t * n + j] : 0.f;
    }
    __syncthreads();
    for (int r = 0; r < 32; r += 8) {
        int j = jb + ty + r, t = tb + tx;
        if (j < n) Xb[(size_t)j * 128 + t] = f2bf(tile[tx][ty + r]);
    }
}

// ---------------- gemm_u via MFMA: Utb = F^T @ Om^T (bf16 out) ----------------
// 64 rows/block, 4 waves x 16 rows. F staged f32->bf16 through padded-u32 LDS.

__global__ __launch_bounds__(256) void gemm_u_mfma(const float* __restrict__ F,
                                                   const u16* __restrict__ Ofrg,
                                                   u16* __restrict__ Utb, int n) {
    __shared__ u32 As32[64][17];   // [row jj][kk2] two bf16 k-values per u32
    int tid = threadIdx.x;
    int w = tid >> 6, l = tid & 63;
    int j0 = blockIdx.x * 64;
    const short8* __restrict__ bfr = (const short8*)Ofrg;
    f32x4 acc[8];
    #pragma unroll
    for (int nt = 0; nt < 8; ++nt) acc[nt] = (f32x4){0.f, 0.f, 0.f, 0.f};
    for (int kf = 0; kf < 8; ++kf) {
        int k0 = kf * 32;
        __syncthreads();
        // stage: 64 j x 32 k -> As32[jj][kk2]; coalesced in j
        #pragma unroll
        for (int r = 0; r < 4; ++r) {
            int idx = r * 256 + tid;          // 0..1023
            int jj = idx & 63, kk2 = idx >> 6;  // kk2 0..15
            int j = j0 + jj;
            float f0 = 0.f, f1 = 0.f;
            if (j < n) {
                f0 = F[(size_t)(k0 + 2 * kk2) * n + j];
                f1 = F[(size_t)(k0 + 2 * kk2 + 1) * n + j];
            }
            As32[jj][kk2] = pack2bf(f0, f1);
        }
        __syncthreads();
        // A-frag: lane l -> row w*16 + (l&15), k-chunk (l>>4)*8 -> 4 u32
        u32 a0 = As32[w * 16 + (l & 15)][(l >> 4) * 4 + 0];
        u32 a1 = As32[w * 16 + (l & 15)][(l >> 4) * 4 + 1];
        u32 a2 = As32[w * 16 + (l & 15)][(l >> 4) * 4 + 2];
        u32 a3 = As32[w * 16 + (l & 15)][(l >> 4) * 4 + 3];
        short8 a;
        a[0] = (short)(a0 & 0xffff); a[1] = (short)(a0 >> 16);
        a[2] = (short)(a1 & 0xffff); a[3] = (short)(a1 >> 16);
        a[4] = (short)(a2 & 0xffff); a[5] = (short)(a2 >> 16);
        a[6] = (short)(a3 & 0xffff); a[7] = (short)(a3 >> 16);
        #pragma unroll
        for (int nt = 0; nt < 8; ++nt) {
            short8 b = bfr[(kf * 8 + nt) * 64 + l];
            acc[nt] = __builtin_amdgcn_mfma_f32_16x16x32_bf16(a, b, acc[nt], 0, 0, 0);
        }
    }
    int rbase = j0 + w * 16 + (l >> 4) * 4;
    int cbase = l & 15;
    #pragma unroll
    for (int nt = 0; nt < 8; ++nt) {
        int col = nt * 16 + cbase;
        #pragma unroll
        for (int i = 0; i < 4; ++i) {
            int row = rbase + i;
            if (row < n) Utb[(size_t)row * 128 + col] = f2bf(acc[nt][i]);
        }
    }
}

// ---------------- reorder bias into MFMA C-fragment layout ----------------

__global__ __launch_bounds__(256) void reorder_bt(const u16* __restrict__ btr,
                                                  uint2* __restrict__ btf) {
    int t = blockIdx.y * 256 + threadIdx.x;   // 0..511
    int idx16 = blockIdx.x;
    int nt = t >> 6, lane = t & 63;
    int r0 = idx16 * 16 + (lane >> 4) * 4;
    int c = nt * 16 + (lane & 15);
    u16 b0 = btr[(size_t)(r0 + 0) * 128 + c];
    u16 b1 = btr[(size_t)(r0 + 1) * 128 + c];
    u16 b2 = btr[(size_t)(r0 + 2) * 128 + c];
    u16 b3 = btr[(size_t)(r0 + 3) * 128 + c];
    uint2 o;
    o.x = (u32)b0 | ((u32)b1 << 16);
    o.y = (u32)b2 | ((u32)b3 << 16);
    btf[(size_t)(idx16 * 8 + nt) * 64 + lane] = o;
}

// ---------------- spmm bf16: Y = X @ A (quarter-wave per row) ----------------

__global__ __launch_bounds__(256) void spmm_bf16(const int* __restrict__ offsets,
                                                 const int2* __restrict__ csr,
                                                 const u16* __restrict__ Xin,
                                                 u16* __restrict__ Yout, int n) {
    int tid = threadIdx.x;
    int wid = tid >> 6, lane = tid & 63;
    int q = lane >> 4, li = lane & 15;
    int j = blockIdx.x * 16 + wid * 4 + q;
    if (j >= n) return;
    int lo = offsets[j], hi = offsets[j + 1];
    const uint4* __restrict__ X4 = (const uint4*)Xin;   // 16 x 16B per row
    float a[8] = {};
    int e = lo;
    for (; e + 8 <= hi; e += 8) {
        int2 c[8];
        #pragma unroll
        for (int u = 0; u < 8; ++u) c[u] = csr[e + u];
        uint4 x[8];
        #pragma unroll
        for (int u = 0; u < 8; ++u) x[u] = X4[(size_t)c[u].x * 16 + li];
        #pragma unroll
        for (int u = 0; u < 8; ++u) {
            float w = __int_as_float(c[u].y);
            a[0] += w * bflo(x[u].x); a[1] += w * bfhi(x[u].x);
            a[2] += w * bflo(x[u].y); a[3] += w * bfhi(x[u].y);
            a[4] += w * bflo(x[u].z); a[5] += w * bfhi(x[u].z);
            a[6] += w * bflo(x[u].w); a[7] += w * bfhi(x[u].w);
        }
    }
    for (; e < hi; ++e) {
        int2 c = csr[e];
        float w = __int_as_float(c.y);
        uint4 x = X4[(size_t)c.x * 16 + li];
        a[0] += w * bflo(x.x); a[1] += w * bfhi(x.x);
        a[2] += w * bflo(x.y); a[3] += w * bfhi(x.y);
        a[4] += w * bflo(x.z); a[5] += w * bfhi(x.z);
        a[6] += w * bflo(x.w); a[7] += w * bfhi(x.w);
    }
    uint4 o;
    o.x = pack2bf(a[0], a[1]);
    o.y = pack2bf(a[2], a[3]);
    o.z = pack2bf(a[4], a[5]);
    o.w = pack2bf(a[6], a[7]);
    ((uint4*)Yout)[(size_t)j * 16 + li] = o;
}

// ---------------- gemm_relu via MFMA: X = relu(Y @ WpT + b) ----------------

__global__ __launch_bounds__(256) void gemm_relu_mfma(const u16* __restrict__ Yb,
                                                      const u16* __restrict__ Bswz,
                                                      const uint2* __restrict__ btf,
                                                      u16* __restrict__ Xb, int n) {
    int tid = threadIdx.x;
    int w = tid >> 6, l = tid & 63;
    int j0 = blockIdx.x * 64 + w * 16;
    int idx16 = blockIdx.x * 4 + w;
    int row_a = j0 + (l & 15);
    bool rowa_ok = row_a < n;
    const short8* __restrict__ yrow = (const short8*)(Yb + (size_t)row_a * 128);
    const short8* __restrict__ bfr = (const short8*)Bswz;
    f32x4 acc[8];
    #pragma unroll
    for (int nt = 0; nt < 8; ++nt) acc[nt] = (f32x4){0.f, 0.f, 0.f, 0.f};
    #pragma unroll
    for (int kf = 0; kf < 4; ++kf) {
        short8 a = {0, 0, 0, 0, 0, 0, 0, 0};
        if (rowa_ok) a = yrow[kf * 4 + (l >> 4)];
        #pragma unroll
        for (int nt = 0; nt < 8; ++nt) {
            short8 b = bfr[(kf * 8 + nt) * 64 + l];
            acc[nt] = __builtin_amdgcn_mfma_f32_16x16x32_bf16(a, b, acc[nt], 0, 0, 0);
        }
    }
    int rbase = j0 + (l >> 4) * 4;
    int cbase = l & 15;
    #pragma unroll
    for (int nt = 0; nt < 8; ++nt) {
        uint2 bb = btf[(size_t)(idx16 * 8 + nt) * 64 + l];
        float bi0 = bflo(bb.x), bi1 = bfhi(bb.x), bi2 = bflo(bb.y), bi3 = bfhi(bb.y);
        int col = nt * 16 + cbase;
        float v0 = acc[nt][0] + bi0;
        float v1 = acc[nt][1] + bi1;
        float v2 = acc[nt][2] + bi2;
        float v3 = acc[nt][3] + bi3;
        if (rbase + 0 < n) Xb[(size_t)(rbase + 0) * 128 + col] = f2bf(v0 > 0.f ? v0 : 0.f);
        if (rbase + 1 < n) Xb[(size_t)(rbase + 1) * 128 + col] = f2bf(v1 > 0.f ? v1 : 0.f);
        if (rbase + 2 < n) Xb[(size_t)(rbase + 2) * 128 + col] = f2bf(v2 > 0.f ? v2 : 0.f);
        if (rbase + 3 < n) Xb[(size_t)(rbase + 3) * 128 + col] = f2bf(v3 > 0.f ? v3 : 0.f);
    }
}

// ---------------- final: normalize rows + H @ Vw^T (bf16 input) ----------------

__global__ __launch_bounds__(256) void final_out(const u16* __restrict__ Xb,
                                                 const float* __restrict__ Vw,
                                                 float* __restrict__ out, int n) {
    __shared__ float Vs[40][132];
    int tid = threadIdx.x;
    int jb = blockIdx.x * 64;
    for (int i = tid; i < 40 * 128; i += 256) {
        int c = i >> 7, k = i & 127;
        Vs[c][(k >> 5) * 33 + (k & 31)] = Vw[i];
    }
    int g = tid >> 2, q = tid & 3;
    int j = jb + g;
    float xs[32];
    float ssq = 0.f;
    if (j < n) {
        const uint4* X4 = (const uint4*)(Xb + (size_t)j * 128) + q * 4;
        #pragma unroll
        for (int v = 0; v < 4; ++v) {
            uint4 u = X4[v];
            xs[v * 8 + 0] = bflo(u.x); xs[v * 8 + 1] = bfhi(u.x);
            xs[v * 8 + 2] = bflo(u.y); xs[v * 8 + 3] = bfhi(u.y);
            xs[v * 8 + 4] = bflo(u.z); xs[v * 8 + 5] = bfhi(u.z);
            xs[v * 8 + 6] = bflo(u.w); xs[v * 8 + 7] = bfhi(u.w);
        }
        #pragma unroll
        for (int m = 0; m < 32; ++m) ssq += xs[m] * xs[m];
    } else {
        #pragma unroll
        for (int m = 0; m < 32; ++m) xs[m] = 0.f;
    }
    ssq += __shfl_xor(ssq, 1, 64);
    ssq += __shfl_xor(ssq, 2, 64);
    float inv = 1.f / fmaxf(sqrtf(ssq), 1e-12f);
    #pragma unroll
    for (int m = 0; m < 32; ++m) xs[m] *= inv;
    __syncthreads();
    float pacc[10];
    #pragma unroll
    for (int cc = 0; cc < 10; ++cc) pacc[cc] = 0.f;
    #pragma unroll 1
    for (int c = 0; c < 40; ++c) {
        const float* vrow = &Vs[c][q * 33];
        float acc = 0.f;
        #pragma unroll
        for (int m = 0; m < 32; ++m) acc += xs[m] * vrow[m];
        acc += __shfl_xor(acc, 1, 64);
        acc += __shfl_xor(acc, 2, 64);
        if ((c & 3) == q) pacc[c >> 2] = acc;
    }
    if (j < n) {
        #pragma unroll
        for (int cc = 0; cc < 10; ++cc) {
            int c = cc * 4 + q;
            out[(size_t)j * 40 + c] = pacc[cc];
        }
    }
}

// ---------------- launch ----------------

extern "C" void kernel_launch(void* const* d_in, const int* in_sizes, int n_in,
                              void* d_out, int out_size, void* d_ws, size_t ws_size,
                              hipStream_t stream) {
    const float* F    = (const float*)d_in[0];   // (256, 50000)
    const float* W    = (const float*)d_in[1];   // (128, 128)
    const float* Om   = (const float*)d_in[2];   // (128, 256)
    const float* Vw   = (const float*)d_in[3];   // (40, 128)
    const float* X0   = (const float*)d_in[4];   // (128, 50000)
    const float* ew   = (const float*)d_in[5];   // (E,)
    const int*   esrc = (const int*)d_in[6];
    const int*   edst = (const int*)d_in[7];
    float* out = (float*)d_out;
    (void)in_sizes; (void)n_in; (void)out_size; (void)ws_size;

    char* ws = (char*)d_ws;
    size_t off = 0;
    auto alloc = [&](size_t bytes) -> void* {
        void* p = ws + off;
        off = (off + bytes + 255) & ~(size_t)255;
        return p;
    };
    float* buf0    = (float*)alloc((size_t)N_NODES * 4);
    float* buf1    = (float*)alloc((size_t)N_NODES * 4);
    float* ss      = (float*)alloc(64 * 4);
    int*   deg     = (int*)  alloc((size_t)(N_NODES + 1) * 4);
    int*   offs_d  = (int*)  alloc((size_t)(N_NODES + 1) * 4);
    int*   cur_d   = (int*)  alloc((size_t)N_NODES * 4);
    int*   bsum    = (int*)  alloc(512 * 4);
    int*   bbase   = (int*)  alloc(512 * 4);
    int2*  csr_d   = (int2*) alloc((size_t)N_EDGES * 8);   // by-dst: (src, w)
    u16*   Bswz    = (u16*)  alloc(128 * 128 * 2);
    u16*   Ofrg    = (u16*)  alloc(128 * 256 * 2);
    u16*   btr     = (u16*)  alloc((size_t)N_NODES * 128 * 2);    // bias row-major
    uint2* btf     = (uint2*)alloc((size_t)3128 * 512 * 8);       // bias C-frag (padded)
    u16*   Utb     = (u16*)  alloc((size_t)N_NODES * 128 * 2);
    u16*   Yb      = (u16*)  alloc((size_t)N_NODES * 128 * 2);
    u16*   Xa      = (u16*)  alloc((size_t)N_NODES * 128 * 2);
    u16*   Xb      = (u16*)  alloc((size_t)N_NODES * 128 * 2);

    hipMemsetAsync(deg, 0, (size_t)(N_NODES + 1) * 4, stream);

    const int n1 = N_NODES + 1;
    const int nb = (n1 + SBLK - 1) / SBLK;   // 196 <= 256

    // ---- CSR build (by dst only) ----
    count_deg<<<(N_EDGES + 255) / 256, 256, 0, stream>>>(edst, deg, N_EDGES);
    scan_local<<<nb, SBLK, 0, stream>>>(deg, offs_d, bsum, n1);
    scan_bsum<<<1, SBLK, 0, stream>>>(bsum, bbase, nb);
    scan_add<<<nb, SBLK, 0, stream>>>(offs_d, cur_d, bbase, n1);
    fill_csr<<<(N_EDGES + 255) / 256, 256, 0, stream>>>(
        esrc, edst, ew, cur_d, csr_d, N_EDGES);

    // ---- power iteration on A^T (rho identical; converged far past f32 eps) ----
    fill_pow<<<(N_NODES + 255) / 256, 256, 0, stream>>>(
        buf0, ss, N_NODES, 1.f / sqrtf((float)N_NODES));
    float* bufs[2] = {buf0, buf1};
    for (int it = 0; it <= PWR_ITERS; ++it) {
        matvec_norm<<<(8 * N_NODES + 255) / 256, 256, 0, stream>>>(
            offs_d, csr_d, bufs[it & 1], ss + it,
            bufs[(it + 1) & 1], ss + it + 1, N_NODES);
    }

    // ---- project W (rho^2 = ss[PWR_ITERS+1]) -> Bswz fragments ----
    project_w<<<128, 128, 0, stream>>>(W, ss + PWR_ITERS + 1, Bswz);

    // ---- b = (Omega_1 @ U) @ A : MFMA gemm (bf16) + bf16 spmm -> C-frag ----
    reorder_om<<<128, 256, 0, stream>>>(Om, Ofrg);
    gemm_u_mfma<<<(N_NODES + 63) / 64, 256, 0, stream>>>(F, Ofrg, Utb, N_NODES);
    spmm_bf16<<<(N_NODES + 15) / 16, 256, 0, stream>>>(offs_d, csr_d, Utb, btr, N_NODES);
    reorder_bt<<<dim3(N_NODES / 16, 2), 256, 0, stream>>>(btr, btf);

    // ---- fixed point (bf16 X/Y, MFMA gemm) ----
    transpose_x0_bf16<<<dim3((N_NODES + 31) / 32, 4), dim3(32, 8), 0, stream>>>(X0, Xa, N_NODES);
    u16* xb2[2] = {Xa, Xb};
    for (int it = 0; it < FP_ITERS; ++it) {
        spmm_bf16<<<(N_NODES + 15) / 16, 256, 0, stream>>>(
            offs_d, csr_d, xb2[it & 1], Yb, N_NODES);
        gemm_relu_mfma<<<(N_NODES + 63) / 64, 256, 0, stream>>>(
            Yb, Bswz, btf, xb2[(it + 1) & 1], N_NODES);
    }

    // ---- output ----
    final_out<<<(N_NODES + 63) / 64, 256, 0, stream>>>(xb2[FP_ITERS & 1], Vw, out, N_NODES);
}